// Round 2
// 318.186 us; speedup vs baseline: 1.0492x; 1.0492x over previous
//
#include <hip/hip_runtime.h>
#include <hip/hip_bf16.h>

// CausalSelfAttention: B=4, N=2048, D=1024, H=16, HD=64. fp32 in / fp32 out.
// R9 (= R8 resubmit; R8 bench was a container-level infra failure, no counters):
//     gemm_lds -> depth-2 pipelined staging (3 LDS buffers, counted vmcnt(4),
//     raw s_barrier so prefetch loads stay in flight across the barrier) +
//     XCD-chunked bijective block swizzle (B-tile + 2MB A-panel hot in per-XCD L2).
//     attn/cvt unchanged from R7.
// ws: Kb/Qb/VT/sa 4x16.78MB = 64MiB; fast path adds wkb+wpb -> 72MiB; xb overlaps sa.

#define NSEQ 2048
#define NHEAD 16
#define DMODEL 1024
#define SCALE2 0.18033688011112042f  // 0.125 * log2(e)

typedef __attribute__((ext_vector_type(8))) short v8s;  // 8 bf16 = 4 VGPRs
typedef __attribute__((ext_vector_type(4))) float v4f;  // MFMA acc

__device__ __forceinline__ float bf2f(unsigned short u) {
    union { unsigned int i; float f; } v;
    v.i = ((unsigned int)u) << 16;
    return v.f;
}
__device__ __forceinline__ unsigned short f2bf(float f) {  // RNE
    unsigned int x = __float_as_uint(f);
    return (unsigned short)((x + 0x7fffu + ((x >> 16) & 1u)) >> 16);
}
__device__ __forceinline__ unsigned short f2bf_rh(float f) {  // round-half-up
    return (unsigned short)((__float_as_uint(f) + 0x8000u) >> 16);
}
__device__ __forceinline__ float fast_exp2(float x) {
#if __has_builtin(__builtin_amdgcn_exp2f)
    return __builtin_amdgcn_exp2f(x);
#else
    return __expf(x * 0.69314718056f);
#endif
}
__device__ __forceinline__ void gld_lds16(const unsigned short* g, unsigned short* l) {
    __builtin_amdgcn_global_load_lds(
        (const __attribute__((address_space(1))) void*)g,
        (__attribute__((address_space(3))) void*)l, 16, 0, 0);
}

// ---------------- cvt: fp32 -> bf16 for x, Wkqv (class-major permute), Wproj -------
// Wkqv in rows h*192 + cls*64 + e -> wkb rows cls*1024 + h*64 + e.
__global__ __launch_bounds__(256) void cvt_bf16(
    const float* __restrict__ x, const float* __restrict__ wk, const float* __restrict__ wp,
    unsigned short* __restrict__ xb, unsigned short* __restrict__ wkb,
    unsigned short* __restrict__ wpb)
{
    const int i = blockIdx.x * 256 + threadIdx.x;   // quad index, 3145728 total
    const float* s; unsigned short* d; int o;
    if (i < 2097152)      { s = x;  d = xb;  o = i; }
    else if (i < 2883584) {
        s = wk; d = wkb;
        const int oi  = i - 2097152;          // 0..786431
        const int row = oi >> 8, cq = oi & 255;
        const int h   = row / 192;
        const int rem = row - h * 192;
        const int cls = rem >> 6, e = rem & 63;
        float4 f = ((const float4*)s)[oi];
        ushort4 u;
        u.x = f2bf(f.x); u.y = f2bf(f.y); u.z = f2bf(f.z); u.w = f2bf(f.w);
        ((ushort4*)d)[(((cls << 10) + (h << 6) + e) << 8) + cq] = u;
        return;
    }
    else                  { s = wp; d = wpb; o = i - 2883584; }
    float4 f = ((const float4*)s)[o];
    ushort4 u;
    u.x = f2bf(f.x); u.y = f2bf(f.y); u.z = f2bf(f.z); u.w = f2bf(f.w);
    ((ushort4*)d)[o] = u;
}

// ---------------- fast MFMA GEMM: bf16 A/B, pipelined global_load_lds staging ------
// C[M,Nc] = A[M,K] @ B[Nc,K]^T + bias. 128x128 tile, 256 thr, BK=32.
// Depth-2 pipeline: tiles t+1,t+2 in flight; end-of-iter s_waitcnt vmcnt(4) waits
// only tile t+1 (t+2's 4 loads cross the raw s_barrier). LDS = 3 x 16KB = 48KB.
// EPI=1: B is class-major-permuted kqv weights; split-write Kb/Qb(scaled)/VT.
// EPI=2: plain fp32 C.
template <int EPI>
__global__ __launch_bounds__(256, 3) void gemm_lds(
    const unsigned short* __restrict__ A, const unsigned short* __restrict__ B,
    const float* __restrict__ bias,
    float* __restrict__ Cf,
    unsigned short* __restrict__ Kb, unsigned short* __restrict__ Qb,
    unsigned short* __restrict__ VTb,
    int M, int Nc, int K)
{
    __shared__ __align__(16) unsigned short Al[3][4096];
    __shared__ __align__(16) unsigned short Bl[3][4096];

    const int t = threadIdx.x, wave = t >> 6, lane = t & 63;
    const int wm = wave >> 1, wn = wave & 1;

    // XCD-chunked bijective swizzle: lin%8 = XCD; within a chunk, iterate 8 m-rows
    // (fastest) per n-col -> B-tile (256KB) + A-panel (2MB) stay hot in per-XCD L2.
    // Valid: gridDim.y == 64, total blocks % 8 == 0 for both launches.
    const int lin = blockIdx.y * gridDim.x + blockIdx.x;
    const int xcd = lin & 7, pos = lin >> 3;
    const int by  = (xcd << 3) + (pos & 7);
    const int bx  = pos >> 3;
    const int m0 = by * 128, n0 = bx * 128;
    const int quad = lane >> 4, c = lane & 15;

    const int g0 = wave * 2, g1 = wave * 2 + 1;
    const int r15 = lane & 15, kg = (lane >> 4) & 3;
    const unsigned short* sA0 = A + (size_t)(m0 + g0 * 16 + r15) * K + kg * 8;
    const unsigned short* sA1 = A + (size_t)(m0 + g1 * 16 + r15) * K + kg * 8;
    const unsigned short* sB0 = B + (size_t)(n0 + g0 * 16 + r15) * K + kg * 8;
    const unsigned short* sB1 = B + (size_t)(n0 + g1 * 16 + r15) * K + kg * 8;

    v4f acc[4][4];
#pragma unroll
    for (int i = 0; i < 4; ++i)
#pragma unroll
        for (int j = 0; j < 4; ++j) acc[i][j] = (v4f){0.f, 0.f, 0.f, 0.f};

    const int fbase = (quad * 16 + c) * 8;
    const int nt = K >> 5;   // 32-wide K tiles (K=1024 -> 32)

    // stage tile tt into LDS buffer b (4 x 16B global_load_lds per thread)
    auto stage = [&](int b, int tt) {
        const int o = tt << 5;
        unsigned short* la = &Al[b][0];
        unsigned short* lb = &Bl[b][0];
        gld_lds16(sA0 + o, la + g0 * 512);
        gld_lds16(sA1 + o, la + g1 * 512);
        gld_lds16(sB0 + o, lb + g0 * 512);
        gld_lds16(sB1 + o, lb + g1 * 512);
    };

    // prologue: tiles 0 and 1 in flight; wait own tile-0 loads (leave tile-1's 4)
    stage(0, 0);
    stage(1, 1);
    asm volatile("s_waitcnt vmcnt(4)" ::: "memory");
    __builtin_amdgcn_s_barrier();

    int cur = 0;
    for (int tt = 0; tt < nt; ++tt) {
        const int nxt = (cur == 2) ? 0 : cur + 1;
        const int b2  = (nxt == 2) ? 0 : nxt + 1;   // buffer (tt+2)%3
        const bool pf = (tt + 2 < nt);
        if (pf) stage(b2, tt + 2);                  // issue-early: overlaps MFMA below

        v8s af[4], bfr[4];
#pragma unroll
        for (int ms = 0; ms < 4; ++ms)
            af[ms] = *(const v8s*)&Al[cur][(wm * 4 + ms) * 512 + fbase];
#pragma unroll
        for (int ns = 0; ns < 4; ++ns)
            bfr[ns] = *(const v8s*)&Bl[cur][(wn * 4 + ns) * 512 + fbase];
#pragma unroll
        for (int ms = 0; ms < 4; ++ms)
#pragma unroll
            for (int ns = 0; ns < 4; ++ns)
                acc[ms][ns] = __builtin_amdgcn_mfma_f32_16x16x32_bf16(
                    af[ms], bfr[ns], acc[ms][ns], 0, 0, 0);

        // wait only tile tt+1's 4 loads; tile tt+2's 4 stay in flight across barrier
        if (pf) { asm volatile("s_waitcnt vmcnt(4)" ::: "memory"); }
        else    { asm volatile("s_waitcnt vmcnt(0)" ::: "memory"); }
        __builtin_amdgcn_s_barrier();
        cur = nxt;
    }

#pragma unroll
    for (int ms = 0; ms < 4; ++ms) {
        const int row0 = m0 + wm * 64 + ms * 16 + quad * 4;
#pragma unroll
        for (int ns = 0; ns < 4; ++ns) {
            const int colbase = n0 + wn * 64 + ns * 16;   // block-uniform, 16-aligned
            float bn, scl = 1.f;
            if (EPI == 2) {
                bn = bias[colbase + c];
            } else {
                const int cls = colbase >> 10;
                const int wi  = colbase & 1023;
                const int h   = wi >> 6, e0 = wi & 63;
                bn = bias[h * 192 + cls * 64 + e0 + c];
                if (cls == 1) scl = SCALE2;
            }
            float v0 = (acc[ms][ns][0] + bn) * scl;
            float v1 = (acc[ms][ns][1] + bn) * scl;
            float v2 = (acc[ms][ns][2] + bn) * scl;
            float v3 = (acc[ms][ns][3] + bn) * scl;
            if (EPI == 2) {
                float* pc = Cf + (size_t)row0 * Nc + colbase + c;
                pc[0] = v0; pc[(size_t)Nc] = v1;
                pc[(size_t)2 * Nc] = v2; pc[(size_t)3 * Nc] = v3;
            } else {
                const int cls = colbase >> 10;
                const int wi  = colbase & 1023;
                const int h   = wi >> 6, e = (wi & 63) + c;
                const int bb  = row0 >> 11, tok0 = row0 & 2047;
                const int bhh = bb * 16 + h;
                if (cls == 2) {            // V -> transposed [bh][dim][tok]
                    ushort4 pk;
                    pk.x = f2bf(v0); pk.y = f2bf(v1); pk.z = f2bf(v2); pk.w = f2bf(v3);
                    *(ushort4*)(VTb + ((size_t)bhh * 64 + e) * 2048 + tok0) = pk;
                } else {                   // K or Q -> [bh][tok][dim]
                    unsigned short* dst = (cls == 0) ? Kb : Qb;
                    const size_t base = ((size_t)bhh * 2048 + tok0) * 64 + e;
                    dst[base]       = f2bf(v0);
                    dst[base + 64]  = f2bf(v1);
                    dst[base + 128] = f2bf(v2);
                    dst[base + 192] = f2bf(v3);
                }
            }
        }
    }
}

// ---------------- fallback GEMM (fp32 sources, VGPR-roundtrip staging) -------------
// EPI=1 uses ORIGINAL (unpermuted) Wkqv col mapping h*192+e; scales Q by SCALE2.
template <bool A_BF16, int EPI>
__global__ __launch_bounds__(256) void gemm_mfma(
    const void* __restrict__ Av, const float* __restrict__ B,
    const float* __restrict__ bias,
    float* __restrict__ Cf,
    unsigned short* __restrict__ Kb, unsigned short* __restrict__ Qb,
    unsigned short* __restrict__ VTb,
    int M, int Nc, int K)
{
    __shared__ __align__(16) unsigned short Al[512 * 8];
    __shared__ __align__(16) unsigned short Bl[512 * 8];

    const int t = threadIdx.x;
    const int wave = t >> 6, lane = t & 63;
    const int wm = wave >> 1, wn = wave & 1;
    const int m0 = blockIdx.y * 128, n0 = blockIdx.x * 128;
    const int quad = lane >> 4, c = lane & 15;

    const int srow = t >> 1, skh = t & 1;
    const int sslot = (srow >> 4) * 64 + (skh * 2) * 16 + (srow & 15);

    v4f acc[4][4];
#pragma unroll
    for (int i = 0; i < 4; ++i)
#pragma unroll
        for (int j = 0; j < 4; ++j) acc[i][j] = (v4f){0.f, 0.f, 0.f, 0.f};

    const unsigned short* pa_u = (const unsigned short*)Av + (size_t)(m0 + srow) * K + skh * 16;
    const float*          pa_f = (const float*)Av          + (size_t)(m0 + srow) * K + skh * 16;
    const float*          pb   = B                          + (size_t)(n0 + srow) * K + skh * 16;

    const int fbase = (quad * 16 + c) * 8;

    for (int k0 = 0; k0 < K; k0 += 32) {
        unsigned short a16[16], b16[16];
        if (A_BF16) {
            uint4 r0 = *(const uint4*)(pa_u + k0);
            uint4 r1 = *(const uint4*)(pa_u + k0 + 8);
            *(uint4*)&a16[0] = r0; *(uint4*)&a16[8] = r1;
        } else {
            float4 f0 = *(const float4*)(pa_f + k0);
            float4 f1 = *(const float4*)(pa_f + k0 + 4);
            float4 f2 = *(const float4*)(pa_f + k0 + 8);
            float4 f3 = *(const float4*)(pa_f + k0 + 12);
            a16[0] = f2bf_rh(f0.x); a16[1] = f2bf_rh(f0.y); a16[2] = f2bf_rh(f0.z); a16[3] = f2bf_rh(f0.w);
            a16[4] = f2bf_rh(f1.x); a16[5] = f2bf_rh(f1.y); a16[6] = f2bf_rh(f1.z); a16[7] = f2bf_rh(f1.w);
            a16[8] = f2bf_rh(f2.x); a16[9] = f2bf_rh(f2.y); a16[10] = f2bf_rh(f2.z); a16[11] = f2bf_rh(f2.w);
            a16[12] = f2bf_rh(f3.x); a16[13] = f2bf_rh(f3.y); a16[14] = f2bf_rh(f3.z); a16[15] = f2bf_rh(f3.w);
        }
        {
            float4 g0 = *(const float4*)(pb + k0);
            float4 g1 = *(const float4*)(pb + k0 + 4);
            float4 g2 = *(const float4*)(pb + k0 + 8);
            float4 g3 = *(const float4*)(pb + k0 + 12);
            b16[0] = f2bf_rh(g0.x); b16[1] = f2bf_rh(g0.y); b16[2] = f2bf_rh(g0.z); b16[3] = f2bf_rh(g0.w);
            b16[4] = f2bf_rh(g1.x); b16[5] = f2bf_rh(g1.y); b16[6] = f2bf_rh(g1.z); b16[7] = f2bf_rh(g1.w);
            b16[8] = f2bf_rh(g2.x); b16[9] = f2bf_rh(g2.y); b16[10] = f2bf_rh(g2.z); b16[11] = f2bf_rh(g2.w);
            b16[12] = f2bf_rh(g3.x); b16[13] = f2bf_rh(g3.y); b16[14] = f2bf_rh(g3.z); b16[15] = f2bf_rh(g3.w);
        }
        __syncthreads();
        *(uint4*)&Al[sslot * 8]        = *(uint4*)&a16[0];
        *(uint4*)&Al[(sslot + 16) * 8] = *(uint4*)&a16[8];
        *(uint4*)&Bl[sslot * 8]        = *(uint4*)&b16[0];
        *(uint4*)&Bl[(sslot + 16) * 8] = *(uint4*)&b16[8];
        __syncthreads();

        v8s af[4], bf[4];
#pragma unroll
        for (int ms = 0; ms < 4; ++ms)
            af[ms] = *(const v8s*)&Al[(wm * 4 + ms) * 512 + fbase];
#pragma unroll
        for (int ns = 0; ns < 4; ++ns)
            bf[ns] = *(const v8s*)&Bl[(wn * 4 + ns) * 512 + fbase];
#pragma unroll
        for (int ms = 0; ms < 4; ++ms)
#pragma unroll
            for (int ns = 0; ns < 4; ++ns)
                acc[ms][ns] = __builtin_amdgcn_mfma_f32_16x16x32_bf16(
                    af[ms], bf[ns], acc[ms][ns], 0, 0, 0);
    }

#pragma unroll
    for (int ms = 0; ms < 4; ++ms) {
        const int row0 = m0 + wm * 64 + ms * 16 + quad * 4;
#pragma unroll
        for (int ns = 0; ns < 4; ++ns) {
            const int colbase = n0 + wn * 64 + ns * 16;
            float bn = (EPI == 2) ? bias[colbase + c] : bias[colbase + c];
            float v0 = acc[ms][ns][0] + bn;
            float v1 = acc[ms][ns][1] + bn;
            float v2 = acc[ms][ns][2] + bn;
            float v3 = acc[ms][ns][3] + bn;
            if (EPI == 2) {
                float* pc = Cf + (size_t)row0 * Nc + colbase + c;
                pc[0] = v0; pc[(size_t)Nc] = v1;
                pc[(size_t)2 * Nc] = v2; pc[(size_t)3 * Nc] = v3;
            } else {
                const int hh = colbase / 192;
                const int eb = colbase - hh * 192;
                const int bb = row0 >> 11, tok0 = row0 & 2047;
                const int bhh = bb * 16 + hh;
                if (eb >= 128) {
                    ushort4 pk;
                    pk.x = f2bf(v0); pk.y = f2bf(v1); pk.z = f2bf(v2); pk.w = f2bf(v3);
                    *(ushort4*)(VTb + ((size_t)bhh * 64 + (eb - 128) + c) * 2048 + tok0) = pk;
                } else {
                    const bool isq = (eb >= 64);
                    const float s = isq ? SCALE2 : 1.f;
                    unsigned short* dst = isq ? Qb : Kb;
                    const int e = (isq ? eb - 64 : eb) + c;
                    const size_t base = ((size_t)bhh * 2048 + tok0) * 64 + e;
                    dst[base]       = f2bf(v0 * s);
                    dst[base + 64]  = f2bf(v1 * s);
                    dst[base + 128] = f2bf(v2 * s);
                    dst[base + 192] = f2bf(v3 * s);
                }
            }
        }
    }
}

// ---------------- barrier-free MFMA flash attention, constant-m softmax -----------
// grid 512 x 256thr. bh = blockIdx&63 (XCD-grouped), bq = blockIdx>>6 (0..7).
// Wave w handles 64 queries of qt in {bq, 15-bq, 16+bq, 31-bq} (uniform 66 kt/block).
// Q pre-scaled by 0.125*log2e; P = exp2(s) raw (|s|<=46 hard bound); l via ones-MFMA.
// K/V fragments read directly from global (L2); only Ps (per-wave) uses LDS.
#define ATTS 72

__global__ __launch_bounds__(256, 2) void attn_mfma(
    const unsigned short* __restrict__ Kbuf,  // [64][2048][64]
    const unsigned short* __restrict__ Qbuf,  // [64][2048][64] (scaled)
    const unsigned short* __restrict__ VT,    // [64][64][2048]
    unsigned short* __restrict__ sa)          // [8192][1024]
{
    __shared__ __align__(16) unsigned short Ps[4][64 * ATTS];

    const int t = threadIdx.x, w = t >> 6, lane = t & 63;
    const int quad = lane >> 4, c = lane & 15;
    const int bh = blockIdx.x & 63, bq = blockIdx.x >> 6;
    const int b = bh >> 4, hh = bh & 15;
    const int qt = (w == 0) ? bq : (w == 1) ? (15 - bq) : (w == 2) ? (16 + bq) : (31 - bq);
    const int qw = qt * 64;
    const size_t gbase = (size_t)bh * (2048 * 64);

    const int rs  = c & 3;
    const int rc0 = (quad ^ rs) * 8, rc1 = 32 + rc0;
    unsigned short* PsW = &Ps[w][0];

    v8s qf[4][2];
#pragma unroll
    for (int qs = 0; qs < 4; ++qs) {
        const unsigned short* qp = Qbuf + gbase + (size_t)(qw + qs * 16 + c) * 64 + quad * 8;
        qf[qs][0] = *(const v8s*)qp;
        qf[qs][1] = *(const v8s*)(qp + 32);
    }
    v4f oacc[4][4], lacc[4];
#pragma unroll
    for (int qs = 0; qs < 4; ++qs) {
        lacc[qs] = (v4f){0.f, 0.f, 0.f, 0.f};
#pragma unroll
        for (int dn = 0; dn < 4; ++dn) oacc[qs][dn] = (v4f){0.f, 0.f, 0.f, 0.f};
    }
    const short oneb = (short)0x3F80;  // bf16 1.0
    const v8s ones = {oneb, oneb, oneb, oneb, oneb, oneb, oneb, oneb};

    const int nkt = qt + 1;
    for (int kt = 0; kt < nkt; ++kt) {
        const int kbase = kt * 64;
        const bool diag = (kt == nkt - 1);   // wave-uniform; kbase == qw on this kt
        // ---- S = Q K^T, P = exp2(S) streamed straight into Ps (A-layout via swizzle)
#pragma unroll
        for (int kn = 0; kn < 4; ++kn) {
            const unsigned short* kp =
                Kbuf + gbase + (size_t)(kbase + kn * 16 + c) * 64 + quad * 8;
            v8s kf0 = *(const v8s*)kp;
            v8s kf1 = *(const v8s*)(kp + 32);
#pragma unroll
            for (int qs = 0; qs < 4; ++qs) {
                v4f s = (v4f){0.f, 0.f, 0.f, 0.f};
                s = __builtin_amdgcn_mfma_f32_16x16x32_bf16(qf[qs][0], kf0, s, 0, 0, 0);
                s = __builtin_amdgcn_mfma_f32_16x16x32_bf16(qf[qs][1], kf1, s, 0, 0, 0);
                if (diag) {
#pragma unroll
                    for (int r = 0; r < 4; ++r)
                        if (kn * 16 + c > qs * 16 + quad * 4 + r) s[r] = -1e30f;
                }
#pragma unroll
                for (int r = 0; r < 4; ++r) {
                    const float p = fast_exp2(s[r]);
                    PsW[(qs * 16 + quad * 4 + r) * ATTS +
                        (((2 * kn + (c >> 3)) ^ r) * 8) + (c & 7)] = f2bf_rh(p);
                }
            }
        }
        // ---- P fragments (A-layout), then O += P V and l += P @ ones
        v8s pa[4][2];
#pragma unroll
        for (int qs = 0; qs < 4; ++qs) {
            pa[qs][0] = *(const v8s*)&PsW[(qs * 16 + c) * ATTS + rc0];
            pa[qs][1] = *(const v8s*)&PsW[(qs * 16 + c) * ATTS + rc1];
        }
#pragma unroll
        for (int dn = 0; dn < 4; ++dn) {
            const unsigned short* vp =
                VT + gbase + (size_t)(dn * 16 + c) * 2048 + kbase + quad * 8;
            v8s vf0 = *(const v8s*)vp;
            v8s vf1 = *(const v8s*)(vp + 32);
#pragma unroll
            for (int qs = 0; qs < 4; ++qs) {
                oacc[qs][dn] = __builtin_amdgcn_mfma_f32_16x16x32_bf16(pa[qs][0], vf0, oacc[qs][dn], 0, 0, 0);
                oacc[qs][dn] = __builtin_amdgcn_mfma_f32_16x16x32_bf16(pa[qs][1], vf1, oacc[qs][dn], 0, 0, 0);
            }
        }
#pragma unroll
        for (int qs = 0; qs < 4; ++qs) {
            lacc[qs] = __builtin_amdgcn_mfma_f32_16x16x32_bf16(pa[qs][0], ones, lacc[qs], 0, 0, 0);
            lacc[qs] = __builtin_amdgcn_mfma_f32_16x16x32_bf16(pa[qs][1], ones, lacc[qs], 0, 0, 0);
        }
    }

    // epilogue: sa[b, qw + qs*16 + quad*4 + r, hh*64 + dn*16 + c]
#pragma unroll
    for (int qs = 0; qs < 4; ++qs) {
        float inv[4];
#pragma unroll
        for (int r = 0; r < 4; ++r) inv[r] = 1.f / lacc[qs][r];
        const size_t obase =
            ((size_t)(b * 2048 + qw + qs * 16 + quad * 4)) * DMODEL + hh * 64;
#pragma unroll
        for (int dn = 0; dn < 4; ++dn)
#pragma unroll
            for (int r = 0; r < 4; ++r)
                sa[obase + (size_t)r * DMODEL + dn * 16 + c] = f2bf(oacc[qs][dn][r] * inv[r]);
    }
}

extern "C" void kernel_launch(void* const* d_in, const int* in_sizes, int n_in,
                              void* d_out, int out_size, void* d_ws, size_t ws_size,
                              hipStream_t stream) {
    const float* x     = (const float*)d_in[0];
    const float* Wkqv  = (const float*)d_in[1];
    const float* bkqv  = (const float*)d_in[2];
    const float* Wproj = (const float*)d_in[3];
    const float* bproj = (const float*)d_in[4];
    float* out = (float*)d_out;

    unsigned short* Kb = (unsigned short*)d_ws;        // [64][2048][64]
    unsigned short* Qb = Kb + (size_t)8388608;         // [64][2048][64]
    unsigned short* VT = Qb + (size_t)8388608;         // [64][64][2048]
    unsigned short* sa = VT + (size_t)8388608;         // [8192][1024]

    const bool fast = ws_size >= 75497472ull;          // 72 MiB
    if (fast) {
        unsigned short* xb  = sa;                      // xb dead before attn writes sa
        unsigned short* wkb = (unsigned short*)d_ws + (size_t)33554432;
        unsigned short* wpb = wkb + (size_t)3145728;
        cvt_bf16<<<12288, 256, 0, stream>>>(x, Wkqv, Wproj, xb, wkb, wpb);
        gemm_lds<1><<<dim3(24, 64), 256, 0, stream>>>(
            xb, wkb, bkqv, nullptr, Kb, Qb, VT, 8192, 3072, 1024);
        attn_mfma<<<512, 256, 0, stream>>>(Kb, Qb, VT, sa);
        gemm_lds<2><<<dim3(8, 64), 256, 0, stream>>>(
            sa, wpb, bproj, out, nullptr, nullptr, nullptr, 8192, 1024, 1024);
    } else {
        gemm_mfma<false, 1><<<dim3(24, 64), 256, 0, stream>>>(
            x, Wkqv, bkqv, nullptr, Kb, Qb, VT, 8192, 3072, 1024);
        attn_mfma<<<512, 256, 0, stream>>>(Kb, Qb, VT, sa);
        gemm_mfma<true, 2><<<dim3(8, 64), 256, 0, stream>>>(
            sa, Wproj, bproj, out, nullptr, nullptr, nullptr, 8192, 1024, 1024);
    }
}

// Round 3
// 312.464 us; speedup vs baseline: 1.0684x; 1.0183x over previous
//
#include <hip/hip_runtime.h>
#include <hip/hip_bf16.h>

// CausalSelfAttention: B=4, N=2048, D=1024, H=16, HD=64. fp32 in / fp32 out.
// R10: gemm -> 256x256 tile, 8 waves (2Mx4N), BK=32, 4-slot LDS ring (128 KiB),
//      2 phases per K-step (8-phase-template style): per phase {ds_read frags,
//      stage 1 half of tile t+3, barrier, setprio(1), 16 MFMA, setprio(0), barrier};
//      counted vmcnt(8) once per K-step (never 0 in main loop) -> 12 loads in
//      flight across barriers. XCD-chunked bijective swizzle kept.
//      attn/cvt unchanged from R7.
// ws: Kb/Qb/VT/sa 4x16.78MB = 64MiB; fast path adds wkb+wpb -> 72MiB; xb overlaps sa.

#define NSEQ 2048
#define NHEAD 16
#define DMODEL 1024
#define SCALE2 0.18033688011112042f  // 0.125 * log2(e)

typedef __attribute__((ext_vector_type(8))) short v8s;  // 8 bf16 = 4 VGPRs
typedef __attribute__((ext_vector_type(4))) float v4f;  // MFMA acc

__device__ __forceinline__ float bf2f(unsigned short u) {
    union { unsigned int i; float f; } v;
    v.i = ((unsigned int)u) << 16;
    return v.f;
}
__device__ __forceinline__ unsigned short f2bf(float f) {  // RNE
    unsigned int x = __float_as_uint(f);
    return (unsigned short)((x + 0x7fffu + ((x >> 16) & 1u)) >> 16);
}
__device__ __forceinline__ unsigned short f2bf_rh(float f) {  // round-half-up
    return (unsigned short)((__float_as_uint(f) + 0x8000u) >> 16);
}
__device__ __forceinline__ float fast_exp2(float x) {
#if __has_builtin(__builtin_amdgcn_exp2f)
    return __builtin_amdgcn_exp2f(x);
#else
    return __expf(x * 0.69314718056f);
#endif
}
__device__ __forceinline__ void gld_lds16(const unsigned short* g, unsigned short* l) {
    __builtin_amdgcn_global_load_lds(
        (const __attribute__((address_space(1))) void*)g,
        (__attribute__((address_space(3))) void*)l, 16, 0, 0);
}

// ---------------- cvt: fp32 -> bf16 for x, Wkqv (class-major permute), Wproj -------
// Wkqv in rows h*192 + cls*64 + e -> wkb rows cls*1024 + h*64 + e.
__global__ __launch_bounds__(256) void cvt_bf16(
    const float* __restrict__ x, const float* __restrict__ wk, const float* __restrict__ wp,
    unsigned short* __restrict__ xb, unsigned short* __restrict__ wkb,
    unsigned short* __restrict__ wpb)
{
    const int i = blockIdx.x * 256 + threadIdx.x;   // quad index, 3145728 total
    const float* s; unsigned short* d; int o;
    if (i < 2097152)      { s = x;  d = xb;  o = i; }
    else if (i < 2883584) {
        s = wk; d = wkb;
        const int oi  = i - 2097152;          // 0..786431
        const int row = oi >> 8, cq = oi & 255;
        const int h   = row / 192;
        const int rem = row - h * 192;
        const int cls = rem >> 6, e = rem & 63;
        float4 f = ((const float4*)s)[oi];
        ushort4 u;
        u.x = f2bf(f.x); u.y = f2bf(f.y); u.z = f2bf(f.z); u.w = f2bf(f.w);
        ((ushort4*)d)[(((cls << 10) + (h << 6) + e) << 8) + cq] = u;
        return;
    }
    else                  { s = wp; d = wpb; o = i - 2883584; }
    float4 f = ((const float4*)s)[o];
    ushort4 u;
    u.x = f2bf(f.x); u.y = f2bf(f.y); u.z = f2bf(f.z); u.w = f2bf(f.w);
    ((ushort4*)d)[o] = u;
}

// ---------------- fast MFMA GEMM: 256x256 tile, 8-phase-style pipelined staging ----
// C[M,Nc] = A[M,K] @ B[Nc,K]^T + bias. 512 thr = 8 waves (2Mx4N), per-wave 128x64.
// 4-slot LDS ring (A 16KB + B 16KB per slot = 128 KiB). Tile t+3 staged while
// computing tile t; vmcnt(8) once per K-step keeps 8 loads in flight across
// barriers. Requires gridDim.y == 32 and K >= 96 (nt >= 3).
// EPI=1: B is class-major-permuted kqv weights; split-write Kb/Qb(scaled)/VT.
// EPI=2: plain fp32 C.
template <int EPI>
__global__ __launch_bounds__(512, 2) void gemm_lds(
    const unsigned short* __restrict__ A, const unsigned short* __restrict__ B,
    const float* __restrict__ bias,
    float* __restrict__ Cf,
    unsigned short* __restrict__ Kb, unsigned short* __restrict__ Qb,
    unsigned short* __restrict__ VTb,
    int M, int Nc, int K)
{
    __shared__ __align__(16) unsigned short Al[4][8192];   // 4 slots x 256rows x 32k
    __shared__ __align__(16) unsigned short Bl[4][8192];

    const int t = threadIdx.x, wave = t >> 6, lane = t & 63;
    const int wm = wave >> 2, wn = wave & 3;               // 2 x 4 wave grid

    // XCD-chunked bijective swizzle (gridDim.y == 32 -> 4 m-rows per XCD chunk):
    // xcd owns 4 consecutive by; within chunk, by fastest -> B-tile (512KB) reused
    // 4x while 2MB A-panel stays hot in per-XCD L2.
    const int lin = blockIdx.y * gridDim.x + blockIdx.x;
    const int xcd = lin & 7, pos = lin >> 3;
    const int by  = (xcd << 2) + (pos & 3);
    const int bx  = pos >> 2;
    const int m0 = by * 256, n0 = bx * 256;
    const int quad = lane >> 4, c = lane & 15;

    // staging: wave w loads 16-row groups {2w, 2w+1} of both A and B.
    const int g0 = wave * 2, g1 = wave * 2 + 1;
    const int r15 = lane & 15, kg = (lane >> 4) & 3;
    const unsigned short* sA0 = A + (size_t)(m0 + g0 * 16 + r15) * K + kg * 8;
    const unsigned short* sA1 = A + (size_t)(m0 + g1 * 16 + r15) * K + kg * 8;
    const unsigned short* sB0 = B + (size_t)(n0 + g0 * 16 + r15) * K + kg * 8;
    const unsigned short* sB1 = B + (size_t)(n0 + g1 * 16 + r15) * K + kg * 8;

    v4f acc[8][4];
#pragma unroll
    for (int i = 0; i < 8; ++i)
#pragma unroll
        for (int j = 0; j < 4; ++j) acc[i][j] = (v4f){0.f, 0.f, 0.f, 0.f};

    const int fbase = (quad * 16 + c) * 8;
    const int nt = K >> 5;   // 32-wide K tiles (K=1024 -> 32)

    auto stageA = [&](int sl, int tt) {
        const int o = tt << 5;
        unsigned short* la = &Al[sl][0];
        gld_lds16(sA0 + o, la + g0 * 512);
        gld_lds16(sA1 + o, la + g1 * 512);
    };
    auto stageB = [&](int sl, int tt) {
        const int o = tt << 5;
        unsigned short* lb = &Bl[sl][0];
        gld_lds16(sB0 + o, lb + g0 * 512);
        gld_lds16(sB1 + o, lb + g1 * 512);
    };

    // prologue: tiles 0,1,2 staged (12 loads); wait tile 0 (leave 8 in flight)
    stageA(0, 0); stageB(0, 0);
    stageA(1, 1); stageB(1, 1);
    stageA(2, 2); stageB(2, 2);
    asm volatile("s_waitcnt vmcnt(8)" ::: "memory");
    __builtin_amdgcn_s_barrier();

    for (int tt = 0; tt < nt; ++tt) {
        const int sl  = tt & 3;
        const int sl3 = (tt + 3) & 3;
        const bool pf = (tt + 3 < nt);

        // ---- phase 1: B frags + A frags ms0-3; stage A(t+3); MFMA quadrant 1 ----
        v8s bfr[4], af[4];
#pragma unroll
        for (int ns = 0; ns < 4; ++ns)
            bfr[ns] = *(const v8s*)&Bl[sl][(wn * 4 + ns) * 512 + fbase];
#pragma unroll
        for (int ms = 0; ms < 4; ++ms)
            af[ms] = *(const v8s*)&Al[sl][(wm * 8 + ms) * 512 + fbase];
        if (pf) stageA(sl3, tt + 3);
        __builtin_amdgcn_s_barrier();
        asm volatile("s_waitcnt lgkmcnt(0)" ::: "memory");
        __builtin_amdgcn_s_setprio(1);
#pragma unroll
        for (int ms = 0; ms < 4; ++ms)
#pragma unroll
            for (int ns = 0; ns < 4; ++ns)
                acc[ms][ns] = __builtin_amdgcn_mfma_f32_16x16x32_bf16(
                    af[ms], bfr[ns], acc[ms][ns], 0, 0, 0);
        __builtin_amdgcn_s_setprio(0);
        __builtin_amdgcn_s_barrier();

        // ---- phase 2: A frags ms4-7; stage B(t+3); MFMA quadrant 2 --------------
        v8s af2[4];
#pragma unroll
        for (int ms = 0; ms < 4; ++ms)
            af2[ms] = *(const v8s*)&Al[sl][(wm * 8 + 4 + ms) * 512 + fbase];
        if (pf) stageB(sl3, tt + 3);
        __builtin_amdgcn_s_barrier();
        asm volatile("s_waitcnt lgkmcnt(0)" ::: "memory");
        __builtin_amdgcn_s_setprio(1);
#pragma unroll
        for (int ms = 0; ms < 4; ++ms)
#pragma unroll
            for (int ns = 0; ns < 4; ++ns)
                acc[4 + ms][ns] = __builtin_amdgcn_mfma_f32_16x16x32_bf16(
                    af2[ms], bfr[ns], acc[4 + ms][ns], 0, 0, 0);
        __builtin_amdgcn_s_setprio(0);
        // counted wait: retire tile tt+1's 4 loads; tiles tt+2, tt+3 stay in flight
        if (pf)                   { asm volatile("s_waitcnt vmcnt(8)" ::: "memory"); }
        else if (tt + 2 < nt)     { asm volatile("s_waitcnt vmcnt(4)" ::: "memory"); }
        else                      { asm volatile("s_waitcnt vmcnt(0)" ::: "memory"); }
        __builtin_amdgcn_s_barrier();
    }

#pragma unroll
    for (int ms = 0; ms < 8; ++ms) {
        const int row0 = m0 + wm * 128 + ms * 16 + quad * 4;
#pragma unroll
        for (int ns = 0; ns < 4; ++ns) {
            const int colbase = n0 + wn * 64 + ns * 16;   // wave-uniform, 16-aligned
            float bn, scl = 1.f;
            if (EPI == 2) {
                bn = bias[colbase + c];
            } else {
                const int cls = colbase >> 10;
                const int wi  = colbase & 1023;
                const int h   = wi >> 6, e0 = wi & 63;
                bn = bias[h * 192 + cls * 64 + e0 + c];
                if (cls == 1) scl = SCALE2;
            }
            float v0 = (acc[ms][ns][0] + bn) * scl;
            float v1 = (acc[ms][ns][1] + bn) * scl;
            float v2 = (acc[ms][ns][2] + bn) * scl;
            float v3 = (acc[ms][ns][3] + bn) * scl;
            if (EPI == 2) {
                float* pc = Cf + (size_t)row0 * Nc + colbase + c;
                pc[0] = v0; pc[(size_t)Nc] = v1;
                pc[(size_t)2 * Nc] = v2; pc[(size_t)3 * Nc] = v3;
            } else {
                const int cls = colbase >> 10;
                const int wi  = colbase & 1023;
                const int h   = wi >> 6, e = (wi & 63) + c;
                const int bb  = row0 >> 11, tok0 = row0 & 2047;
                const int bhh = bb * 16 + h;
                if (cls == 2) {            // V -> transposed [bh][dim][tok]
                    ushort4 pk;
                    pk.x = f2bf(v0); pk.y = f2bf(v1); pk.z = f2bf(v2); pk.w = f2bf(v3);
                    *(ushort4*)(VTb + ((size_t)bhh * 64 + e) * 2048 + tok0) = pk;
                } else {                   // K or Q -> [bh][tok][dim]
                    unsigned short* dst = (cls == 0) ? Kb : Qb;
                    const size_t base = ((size_t)bhh * 2048 + tok0) * 64 + e;
                    dst[base]       = f2bf(v0);
                    dst[base + 64]  = f2bf(v1);
                    dst[base + 128] = f2bf(v2);
                    dst[base + 192] = f2bf(v3);
                }
            }
        }
    }
}

// ---------------- fallback GEMM (fp32 sources, VGPR-roundtrip staging) -------------
// EPI=1 uses ORIGINAL (unpermuted) Wkqv col mapping h*192+e; scales Q by SCALE2.
template <bool A_BF16, int EPI>
__global__ __launch_bounds__(256) void gemm_mfma(
    const void* __restrict__ Av, const float* __restrict__ B,
    const float* __restrict__ bias,
    float* __restrict__ Cf,
    unsigned short* __restrict__ Kb, unsigned short* __restrict__ Qb,
    unsigned short* __restrict__ VTb,
    int M, int Nc, int K)
{
    __shared__ __align__(16) unsigned short Al[512 * 8];
    __shared__ __align__(16) unsigned short Bl[512 * 8];

    const int t = threadIdx.x;
    const int wave = t >> 6, lane = t & 63;
    const int wm = wave >> 1, wn = wave & 1;
    const int m0 = blockIdx.y * 128, n0 = blockIdx.x * 128;
    const int quad = lane >> 4, c = lane & 15;

    const int srow = t >> 1, skh = t & 1;
    const int sslot = (srow >> 4) * 64 + (skh * 2) * 16 + (srow & 15);

    v4f acc[4][4];
#pragma unroll
    for (int i = 0; i < 4; ++i)
#pragma unroll
        for (int j = 0; j < 4; ++j) acc[i][j] = (v4f){0.f, 0.f, 0.f, 0.f};

    const unsigned short* pa_u = (const unsigned short*)Av + (size_t)(m0 + srow) * K + skh * 16;
    const float*          pa_f = (const float*)Av          + (size_t)(m0 + srow) * K + skh * 16;
    const float*          pb   = B                          + (size_t)(n0 + srow) * K + skh * 16;

    const int fbase = (quad * 16 + c) * 8;

    for (int k0 = 0; k0 < K; k0 += 32) {
        unsigned short a16[16], b16[16];
        if (A_BF16) {
            uint4 r0 = *(const uint4*)(pa_u + k0);
            uint4 r1 = *(const uint4*)(pa_u + k0 + 8);
            *(uint4*)&a16[0] = r0; *(uint4*)&a16[8] = r1;
        } else {
            float4 f0 = *(const float4*)(pa_f + k0);
            float4 f1 = *(const float4*)(pa_f + k0 + 4);
            float4 f2 = *(const float4*)(pa_f + k0 + 8);
            float4 f3 = *(const float4*)(pa_f + k0 + 12);
            a16[0] = f2bf_rh(f0.x); a16[1] = f2bf_rh(f0.y); a16[2] = f2bf_rh(f0.z); a16[3] = f2bf_rh(f0.w);
            a16[4] = f2bf_rh(f1.x); a16[5] = f2bf_rh(f1.y); a16[6] = f2bf_rh(f1.z); a16[7] = f2bf_rh(f1.w);
            a16[8] = f2bf_rh(f2.x); a16[9] = f2bf_rh(f2.y); a16[10] = f2bf_rh(f2.z); a16[11] = f2bf_rh(f2.w);
            a16[12] = f2bf_rh(f3.x); a16[13] = f2bf_rh(f3.y); a16[14] = f2bf_rh(f3.z); a16[15] = f2bf_rh(f3.w);
        }
        {
            float4 g0 = *(const float4*)(pb + k0);
            float4 g1 = *(const float4*)(pb + k0 + 4);
            float4 g2 = *(const float4*)(pb + k0 + 8);
            float4 g3 = *(const float4*)(pb + k0 + 12);
            b16[0] = f2bf_rh(g0.x); b16[1] = f2bf_rh(g0.y); b16[2] = f2bf_rh(g0.z); b16[3] = f2bf_rh(g0.w);
            b16[4] = f2bf_rh(g1.x); b16[5] = f2bf_rh(g1.y); b16[6] = f2bf_rh(g1.z); b16[7] = f2bf_rh(g1.w);
            b16[8] = f2bf_rh(g2.x); b16[9] = f2bf_rh(g2.y); b16[10] = f2bf_rh(g2.z); b16[11] = f2bf_rh(g2.w);
            b16[12] = f2bf_rh(g3.x); b16[13] = f2bf_rh(g3.y); b16[14] = f2bf_rh(g3.z); b16[15] = f2bf_rh(g3.w);
        }
        __syncthreads();
        *(uint4*)&Al[sslot * 8]        = *(uint4*)&a16[0];
        *(uint4*)&Al[(sslot + 16) * 8] = *(uint4*)&a16[8];
        *(uint4*)&Bl[sslot * 8]        = *(uint4*)&b16[0];
        *(uint4*)&Bl[(sslot + 16) * 8] = *(uint4*)&b16[8];
        __syncthreads();

        v8s af[4], bf[4];
#pragma unroll
        for (int ms = 0; ms < 4; ++ms)
            af[ms] = *(const v8s*)&Al[(wm * 4 + ms) * 512 + fbase];
#pragma unroll
        for (int ns = 0; ns < 4; ++ns)
            bf[ns] = *(const v8s*)&Bl[(wn * 4 + ns) * 512 + fbase];
#pragma unroll
        for (int ms = 0; ms < 4; ++ms)
#pragma unroll
            for (int ns = 0; ns < 4; ++ns)
                acc[ms][ns] = __builtin_amdgcn_mfma_f32_16x16x32_bf16(
                    af[ms], bf[ns], acc[ms][ns], 0, 0, 0);
    }

#pragma unroll
    for (int ms = 0; ms < 4; ++ms) {
        const int row0 = m0 + wm * 64 + ms * 16 + quad * 4;
#pragma unroll
        for (int ns = 0; ns < 4; ++ns) {
            const int colbase = n0 + wn * 64 + ns * 16;
            float bn = (EPI == 2) ? bias[colbase + c] : bias[colbase + c];
            float v0 = acc[ms][ns][0] + bn;
            float v1 = acc[ms][ns][1] + bn;
            float v2 = acc[ms][ns][2] + bn;
            float v3 = acc[ms][ns][3] + bn;
            if (EPI == 2) {
                float* pc = Cf + (size_t)row0 * Nc + colbase + c;
                pc[0] = v0; pc[(size_t)Nc] = v1;
                pc[(size_t)2 * Nc] = v2; pc[(size_t)3 * Nc] = v3;
            } else {
                const int hh = colbase / 192;
                const int eb = colbase - hh * 192;
                const int bb = row0 >> 11, tok0 = row0 & 2047;
                const int bhh = bb * 16 + hh;
                if (eb >= 128) {
                    ushort4 pk;
                    pk.x = f2bf(v0); pk.y = f2bf(v1); pk.z = f2bf(v2); pk.w = f2bf(v3);
                    *(ushort4*)(VTb + ((size_t)bhh * 64 + (eb - 128) + c) * 2048 + tok0) = pk;
                } else {
                    const bool isq = (eb >= 64);
                    const float s = isq ? SCALE2 : 1.f;
                    unsigned short* dst = isq ? Qb : Kb;
                    const int e = (isq ? eb - 64 : eb) + c;
                    const size_t base = ((size_t)bhh * 2048 + tok0) * 64 + e;
                    dst[base]       = f2bf(v0 * s);
                    dst[base + 64]  = f2bf(v1 * s);
                    dst[base + 128] = f2bf(v2 * s);
                    dst[base + 192] = f2bf(v3 * s);
                }
            }
        }
    }
}

// ---------------- barrier-free MFMA flash attention, constant-m softmax -----------
// grid 512 x 256thr. bh = blockIdx&63 (XCD-grouped), bq = blockIdx>>6 (0..7).
// Wave w handles 64 queries of qt in {bq, 15-bq, 16+bq, 31-bq} (uniform 66 kt/block).
// Q pre-scaled by 0.125*log2e; P = exp2(s) raw (|s|<=46 hard bound); l via ones-MFMA.
// K/V fragments read directly from global (L2); only Ps (per-wave) uses LDS.
#define ATTS 72

__global__ __launch_bounds__(256, 2) void attn_mfma(
    const unsigned short* __restrict__ Kbuf,  // [64][2048][64]
    const unsigned short* __restrict__ Qbuf,  // [64][2048][64] (scaled)
    const unsigned short* __restrict__ VT,    // [64][64][2048]
    unsigned short* __restrict__ sa)          // [8192][1024]
{
    __shared__ __align__(16) unsigned short Ps[4][64 * ATTS];

    const int t = threadIdx.x, w = t >> 6, lane = t & 63;
    const int quad = lane >> 4, c = lane & 15;
    const int bh = blockIdx.x & 63, bq = blockIdx.x >> 6;
    const int b = bh >> 4, hh = bh & 15;
    const int qt = (w == 0) ? bq : (w == 1) ? (15 - bq) : (w == 2) ? (16 + bq) : (31 - bq);
    const int qw = qt * 64;
    const size_t gbase = (size_t)bh * (2048 * 64);

    const int rs  = c & 3;
    const int rc0 = (quad ^ rs) * 8, rc1 = 32 + rc0;
    unsigned short* PsW = &Ps[w][0];

    v8s qf[4][2];
#pragma unroll
    for (int qs = 0; qs < 4; ++qs) {
        const unsigned short* qp = Qbuf + gbase + (size_t)(qw + qs * 16 + c) * 64 + quad * 8;
        qf[qs][0] = *(const v8s*)qp;
        qf[qs][1] = *(const v8s*)(qp + 32);
    }
    v4f oacc[4][4], lacc[4];
#pragma unroll
    for (int qs = 0; qs < 4; ++qs) {
        lacc[qs] = (v4f){0.f, 0.f, 0.f, 0.f};
#pragma unroll
        for (int dn = 0; dn < 4; ++dn) oacc[qs][dn] = (v4f){0.f, 0.f, 0.f, 0.f};
    }
    const short oneb = (short)0x3F80;  // bf16 1.0
    const v8s ones = {oneb, oneb, oneb, oneb, oneb, oneb, oneb, oneb};

    const int nkt = qt + 1;
    for (int kt = 0; kt < nkt; ++kt) {
        const int kbase = kt * 64;
        const bool diag = (kt == nkt - 1);   // wave-uniform; kbase == qw on this kt
        // ---- S = Q K^T, P = exp2(S) streamed straight into Ps (A-layout via swizzle)
#pragma unroll
        for (int kn = 0; kn < 4; ++kn) {
            const unsigned short* kp =
                Kbuf + gbase + (size_t)(kbase + kn * 16 + c) * 64 + quad * 8;
            v8s kf0 = *(const v8s*)kp;
            v8s kf1 = *(const v8s*)(kp + 32);
#pragma unroll
            for (int qs = 0; qs < 4; ++qs) {
                v4f s = (v4f){0.f, 0.f, 0.f, 0.f};
                s = __builtin_amdgcn_mfma_f32_16x16x32_bf16(qf[qs][0], kf0, s, 0, 0, 0);
                s = __builtin_amdgcn_mfma_f32_16x16x32_bf16(qf[qs][1], kf1, s, 0, 0, 0);
                if (diag) {
#pragma unroll
                    for (int r = 0; r < 4; ++r)
                        if (kn * 16 + c > qs * 16 + quad * 4 + r) s[r] = -1e30f;
                }
#pragma unroll
                for (int r = 0; r < 4; ++r) {
                    const float p = fast_exp2(s[r]);
                    PsW[(qs * 16 + quad * 4 + r) * ATTS +
                        (((2 * kn + (c >> 3)) ^ r) * 8) + (c & 7)] = f2bf_rh(p);
                }
            }
        }
        // ---- P fragments (A-layout), then O += P V and l += P @ ones
        v8s pa[4][2];
#pragma unroll
        for (int qs = 0; qs < 4; ++qs) {
            pa[qs][0] = *(const v8s*)&PsW[(qs * 16 + c) * ATTS + rc0];
            pa[qs][1] = *(const v8s*)&PsW[(qs * 16 + c) * ATTS + rc1];
        }
#pragma unroll
        for (int dn = 0; dn < 4; ++dn) {
            const unsigned short* vp =
                VT + gbase + (size_t)(dn * 16 + c) * 2048 + kbase + quad * 8;
            v8s vf0 = *(const v8s*)vp;
            v8s vf1 = *(const v8s*)(vp + 32);
#pragma unroll
            for (int qs = 0; qs < 4; ++qs) {
                oacc[qs][dn] = __builtin_amdgcn_mfma_f32_16x16x32_bf16(pa[qs][0], vf0, oacc[qs][dn], 0, 0, 0);
                oacc[qs][dn] = __builtin_amdgcn_mfma_f32_16x16x32_bf16(pa[qs][1], vf1, oacc[qs][dn], 0, 0, 0);
            }
        }
#pragma unroll
        for (int qs = 0; qs < 4; ++qs) {
            lacc[qs] = __builtin_amdgcn_mfma_f32_16x16x32_bf16(pa[qs][0], ones, lacc[qs], 0, 0, 0);
            lacc[qs] = __builtin_amdgcn_mfma_f32_16x16x32_bf16(pa[qs][1], ones, lacc[qs], 0, 0, 0);
        }
    }

    // epilogue: sa[b, qw + qs*16 + quad*4 + r, hh*64 + dn*16 + c]
#pragma unroll
    for (int qs = 0; qs < 4; ++qs) {
        float inv[4];
#pragma unroll
        for (int r = 0; r < 4; ++r) inv[r] = 1.f / lacc[qs][r];
        const size_t obase =
            ((size_t)(b * 2048 + qw + qs * 16 + quad * 4)) * DMODEL + hh * 64;
#pragma unroll
        for (int dn = 0; dn < 4; ++dn)
#pragma unroll
            for (int r = 0; r < 4; ++r)
                sa[obase + (size_t)r * DMODEL + dn * 16 + c] = f2bf(oacc[qs][dn][r] * inv[r]);
    }
}

extern "C" void kernel_launch(void* const* d_in, const int* in_sizes, int n_in,
                              void* d_out, int out_size, void* d_ws, size_t ws_size,
                              hipStream_t stream) {
    const float* x     = (const float*)d_in[0];
    const float* Wkqv  = (const float*)d_in[1];
    const float* bkqv  = (const float*)d_in[2];
    const float* Wproj = (const float*)d_in[3];
    const float* bproj = (const float*)d_in[4];
    float* out = (float*)d_out;

    unsigned short* Kb = (unsigned short*)d_ws;        // [64][2048][64]
    unsigned short* Qb = Kb + (size_t)8388608;         // [64][2048][64]
    unsigned short* VT = Qb + (size_t)8388608;         // [64][64][2048]
    unsigned short* sa = VT + (size_t)8388608;         // [8192][1024]

    const bool fast = ws_size >= 75497472ull;          // 72 MiB
    if (fast) {
        unsigned short* xb  = sa;                      // xb dead before attn writes sa
        unsigned short* wkb = (unsigned short*)d_ws + (size_t)33554432;
        unsigned short* wpb = wkb + (size_t)3145728;
        cvt_bf16<<<12288, 256, 0, stream>>>(x, Wkqv, Wproj, xb, wkb, wpb);
        gemm_lds<1><<<dim3(12, 32), 512, 0, stream>>>(
            xb, wkb, bkqv, nullptr, Kb, Qb, VT, 8192, 3072, 1024);
        attn_mfma<<<512, 256, 0, stream>>>(Kb, Qb, VT, sa);
        gemm_lds<2><<<dim3(4, 32), 512, 0, stream>>>(
            sa, wpb, bproj, out, nullptr, nullptr, nullptr, 8192, 1024, 1024);
    } else {
        gemm_mfma<false, 1><<<dim3(24, 64), 256, 0, stream>>>(
            x, Wkqv, bkqv, nullptr, Kb, Qb, VT, 8192, 3072, 1024);
        attn_mfma<<<512, 256, 0, stream>>>(Kb, Qb, VT, sa);
        gemm_mfma<true, 2><<<dim3(8, 64), 256, 0, stream>>>(
            sa, Wproj, bproj, out, nullptr, nullptr, nullptr, 8192, 1024, 1024);
    }
}

// Round 4
// 305.507 us; speedup vs baseline: 1.0928x; 1.0228x over previous
//
#include <hip/hip_runtime.h>
#include <hip/hip_bf16.h>

// CausalSelfAttention: B=4, N=2048, D=1024, H=16, HD=64. fp32 in / fp32 out.
// R11: attn -> (1) Ps double-buffered per kt (removes PV(kt) vs QK(kt+1) LDS WAR
//      serialization; LDS 36.9->73.7KB, still 2 blocks/CU), (2) V fragments
//      prefetched at iteration top (one exposed L2 latency per kt instead of two;
//      vmcnt FIFO means the K wait also covers V arrival). gemm/cvt unchanged R10.
// ws: Kb/Qb/VT/sa 4x16.78MB = 64MiB; fast path adds wkb+wpb -> 72MiB; xb overlaps sa.

#define NSEQ 2048
#define NHEAD 16
#define DMODEL 1024
#define SCALE2 0.18033688011112042f  // 0.125 * log2(e)

typedef __attribute__((ext_vector_type(8))) short v8s;  // 8 bf16 = 4 VGPRs
typedef __attribute__((ext_vector_type(4))) float v4f;  // MFMA acc

__device__ __forceinline__ float bf2f(unsigned short u) {
    union { unsigned int i; float f; } v;
    v.i = ((unsigned int)u) << 16;
    return v.f;
}
__device__ __forceinline__ unsigned short f2bf(float f) {  // RNE
    unsigned int x = __float_as_uint(f);
    return (unsigned short)((x + 0x7fffu + ((x >> 16) & 1u)) >> 16);
}
__device__ __forceinline__ unsigned short f2bf_rh(float f) {  // round-half-up
    return (unsigned short)((__float_as_uint(f) + 0x8000u) >> 16);
}
__device__ __forceinline__ float fast_exp2(float x) {
#if __has_builtin(__builtin_amdgcn_exp2f)
    return __builtin_amdgcn_exp2f(x);
#else
    return __expf(x * 0.69314718056f);
#endif
}
__device__ __forceinline__ void gld_lds16(const unsigned short* g, unsigned short* l) {
    __builtin_amdgcn_global_load_lds(
        (const __attribute__((address_space(1))) void*)g,
        (__attribute__((address_space(3))) void*)l, 16, 0, 0);
}

// ---------------- cvt: fp32 -> bf16 for x, Wkqv (class-major permute), Wproj -------
// Wkqv in rows h*192 + cls*64 + e -> wkb rows cls*1024 + h*64 + e.
__global__ __launch_bounds__(256) void cvt_bf16(
    const float* __restrict__ x, const float* __restrict__ wk, const float* __restrict__ wp,
    unsigned short* __restrict__ xb, unsigned short* __restrict__ wkb,
    unsigned short* __restrict__ wpb)
{
    const int i = blockIdx.x * 256 + threadIdx.x;   // quad index, 3145728 total
    const float* s; unsigned short* d; int o;
    if (i < 2097152)      { s = x;  d = xb;  o = i; }
    else if (i < 2883584) {
        s = wk; d = wkb;
        const int oi  = i - 2097152;          // 0..786431
        const int row = oi >> 8, cq = oi & 255;
        const int h   = row / 192;
        const int rem = row - h * 192;
        const int cls = rem >> 6, e = rem & 63;
        float4 f = ((const float4*)s)[oi];
        ushort4 u;
        u.x = f2bf(f.x); u.y = f2bf(f.y); u.z = f2bf(f.z); u.w = f2bf(f.w);
        ((ushort4*)d)[(((cls << 10) + (h << 6) + e) << 8) + cq] = u;
        return;
    }
    else                  { s = wp; d = wpb; o = i - 2883584; }
    float4 f = ((const float4*)s)[o];
    ushort4 u;
    u.x = f2bf(f.x); u.y = f2bf(f.y); u.z = f2bf(f.z); u.w = f2bf(f.w);
    ((ushort4*)d)[o] = u;
}

// ---------------- fast MFMA GEMM: 256x256 tile, 8-phase-style pipelined staging ----
// C[M,Nc] = A[M,K] @ B[Nc,K]^T + bias. 512 thr = 8 waves (2Mx4N), per-wave 128x64.
// 4-slot LDS ring (A 16KB + B 16KB per slot = 128 KiB). Tile t+3 staged while
// computing tile t; vmcnt(8) once per K-step keeps 8 loads in flight across
// barriers. Requires gridDim.y == 32 and K >= 96 (nt >= 3).
// EPI=1: B is class-major-permuted kqv weights; split-write Kb/Qb(scaled)/VT.
// EPI=2: plain fp32 C.
template <int EPI>
__global__ __launch_bounds__(512, 2) void gemm_lds(
    const unsigned short* __restrict__ A, const unsigned short* __restrict__ B,
    const float* __restrict__ bias,
    float* __restrict__ Cf,
    unsigned short* __restrict__ Kb, unsigned short* __restrict__ Qb,
    unsigned short* __restrict__ VTb,
    int M, int Nc, int K)
{
    __shared__ __align__(16) unsigned short Al[4][8192];   // 4 slots x 256rows x 32k
    __shared__ __align__(16) unsigned short Bl[4][8192];

    const int t = threadIdx.x, wave = t >> 6, lane = t & 63;
    const int wm = wave >> 2, wn = wave & 3;               // 2 x 4 wave grid

    // XCD-chunked bijective swizzle (gridDim.y == 32 -> 4 m-rows per XCD chunk):
    // xcd owns 4 consecutive by; within chunk, by fastest -> B-tile (512KB) reused
    // 4x while 2MB A-panel stays hot in per-XCD L2.
    const int lin = blockIdx.y * gridDim.x + blockIdx.x;
    const int xcd = lin & 7, pos = lin >> 3;
    const int by  = (xcd << 2) + (pos & 3);
    const int bx  = pos >> 2;
    const int m0 = by * 256, n0 = bx * 256;
    const int quad = lane >> 4, c = lane & 15;

    // staging: wave w loads 16-row groups {2w, 2w+1} of both A and B.
    const int g0 = wave * 2, g1 = wave * 2 + 1;
    const int r15 = lane & 15, kg = (lane >> 4) & 3;
    const unsigned short* sA0 = A + (size_t)(m0 + g0 * 16 + r15) * K + kg * 8;
    const unsigned short* sA1 = A + (size_t)(m0 + g1 * 16 + r15) * K + kg * 8;
    const unsigned short* sB0 = B + (size_t)(n0 + g0 * 16 + r15) * K + kg * 8;
    const unsigned short* sB1 = B + (size_t)(n0 + g1 * 16 + r15) * K + kg * 8;

    v4f acc[8][4];
#pragma unroll
    for (int i = 0; i < 8; ++i)
#pragma unroll
        for (int j = 0; j < 4; ++j) acc[i][j] = (v4f){0.f, 0.f, 0.f, 0.f};

    const int fbase = (quad * 16 + c) * 8;
    const int nt = K >> 5;   // 32-wide K tiles (K=1024 -> 32)

    auto stageA = [&](int sl, int tt) {
        const int o = tt << 5;
        unsigned short* la = &Al[sl][0];
        gld_lds16(sA0 + o, la + g0 * 512);
        gld_lds16(sA1 + o, la + g1 * 512);
    };
    auto stageB = [&](int sl, int tt) {
        const int o = tt << 5;
        unsigned short* lb = &Bl[sl][0];
        gld_lds16(sB0 + o, lb + g0 * 512);
        gld_lds16(sB1 + o, lb + g1 * 512);
    };

    // prologue: tiles 0,1,2 staged (12 loads); wait tile 0 (leave 8 in flight)
    stageA(0, 0); stageB(0, 0);
    stageA(1, 1); stageB(1, 1);
    stageA(2, 2); stageB(2, 2);
    asm volatile("s_waitcnt vmcnt(8)" ::: "memory");
    __builtin_amdgcn_s_barrier();

    for (int tt = 0; tt < nt; ++tt) {
        const int sl  = tt & 3;
        const int sl3 = (tt + 3) & 3;
        const bool pf = (tt + 3 < nt);

        // ---- phase 1: B frags + A frags ms0-3; stage A(t+3); MFMA quadrant 1 ----
        v8s bfr[4], af[4];
#pragma unroll
        for (int ns = 0; ns < 4; ++ns)
            bfr[ns] = *(const v8s*)&Bl[sl][(wn * 4 + ns) * 512 + fbase];
#pragma unroll
        for (int ms = 0; ms < 4; ++ms)
            af[ms] = *(const v8s*)&Al[sl][(wm * 8 + ms) * 512 + fbase];
        if (pf) stageA(sl3, tt + 3);
        __builtin_amdgcn_s_barrier();
        asm volatile("s_waitcnt lgkmcnt(0)" ::: "memory");
        __builtin_amdgcn_s_setprio(1);
#pragma unroll
        for (int ms = 0; ms < 4; ++ms)
#pragma unroll
            for (int ns = 0; ns < 4; ++ns)
                acc[ms][ns] = __builtin_amdgcn_mfma_f32_16x16x32_bf16(
                    af[ms], bfr[ns], acc[ms][ns], 0, 0, 0);
        __builtin_amdgcn_s_setprio(0);
        __builtin_amdgcn_s_barrier();

        // ---- phase 2: A frags ms4-7; stage B(t+3); MFMA quadrant 2 --------------
        v8s af2[4];
#pragma unroll
        for (int ms = 0; ms < 4; ++ms)
            af2[ms] = *(const v8s*)&Al[sl][(wm * 8 + 4 + ms) * 512 + fbase];
        if (pf) stageB(sl3, tt + 3);
        __builtin_amdgcn_s_barrier();
        asm volatile("s_waitcnt lgkmcnt(0)" ::: "memory");
        __builtin_amdgcn_s_setprio(1);
#pragma unroll
        for (int ms = 0; ms < 4; ++ms)
#pragma unroll
            for (int ns = 0; ns < 4; ++ns)
                acc[4 + ms][ns] = __builtin_amdgcn_mfma_f32_16x16x32_bf16(
                    af2[ms], bfr[ns], acc[4 + ms][ns], 0, 0, 0);
        __builtin_amdgcn_s_setprio(0);
        // counted wait: retire tile tt+1's 4 loads; tiles tt+2, tt+3 stay in flight
        if (pf)                   { asm volatile("s_waitcnt vmcnt(8)" ::: "memory"); }
        else if (tt + 2 < nt)     { asm volatile("s_waitcnt vmcnt(4)" ::: "memory"); }
        else                      { asm volatile("s_waitcnt vmcnt(0)" ::: "memory"); }
        __builtin_amdgcn_s_barrier();
    }

#pragma unroll
    for (int ms = 0; ms < 8; ++ms) {
        const int row0 = m0 + wm * 128 + ms * 16 + quad * 4;
#pragma unroll
        for (int ns = 0; ns < 4; ++ns) {
            const int colbase = n0 + wn * 64 + ns * 16;   // wave-uniform, 16-aligned
            float bn, scl = 1.f;
            if (EPI == 2) {
                bn = bias[colbase + c];
            } else {
                const int cls = colbase >> 10;
                const int wi  = colbase & 1023;
                const int h   = wi >> 6, e0 = wi & 63;
                bn = bias[h * 192 + cls * 64 + e0 + c];
                if (cls == 1) scl = SCALE2;
            }
            float v0 = (acc[ms][ns][0] + bn) * scl;
            float v1 = (acc[ms][ns][1] + bn) * scl;
            float v2 = (acc[ms][ns][2] + bn) * scl;
            float v3 = (acc[ms][ns][3] + bn) * scl;
            if (EPI == 2) {
                float* pc = Cf + (size_t)row0 * Nc + colbase + c;
                pc[0] = v0; pc[(size_t)Nc] = v1;
                pc[(size_t)2 * Nc] = v2; pc[(size_t)3 * Nc] = v3;
            } else {
                const int cls = colbase >> 10;
                const int wi  = colbase & 1023;
                const int h   = wi >> 6, e = (wi & 63) + c;
                const int bb  = row0 >> 11, tok0 = row0 & 2047;
                const int bhh = bb * 16 + h;
                if (cls == 2) {            // V -> transposed [bh][dim][tok]
                    ushort4 pk;
                    pk.x = f2bf(v0); pk.y = f2bf(v1); pk.z = f2bf(v2); pk.w = f2bf(v3);
                    *(ushort4*)(VTb + ((size_t)bhh * 64 + e) * 2048 + tok0) = pk;
                } else {                   // K or Q -> [bh][tok][dim]
                    unsigned short* dst = (cls == 0) ? Kb : Qb;
                    const size_t base = ((size_t)bhh * 2048 + tok0) * 64 + e;
                    dst[base]       = f2bf(v0);
                    dst[base + 64]  = f2bf(v1);
                    dst[base + 128] = f2bf(v2);
                    dst[base + 192] = f2bf(v3);
                }
            }
        }
    }
}

// ---------------- fallback GEMM (fp32 sources, VGPR-roundtrip staging) -------------
// EPI=1 uses ORIGINAL (unpermuted) Wkqv col mapping h*192+e; scales Q by SCALE2.
template <bool A_BF16, int EPI>
__global__ __launch_bounds__(256) void gemm_mfma(
    const void* __restrict__ Av, const float* __restrict__ B,
    const float* __restrict__ bias,
    float* __restrict__ Cf,
    unsigned short* __restrict__ Kb, unsigned short* __restrict__ Qb,
    unsigned short* __restrict__ VTb,
    int M, int Nc, int K)
{
    __shared__ __align__(16) unsigned short Al[512 * 8];
    __shared__ __align__(16) unsigned short Bl[512 * 8];

    const int t = threadIdx.x;
    const int wave = t >> 6, lane = t & 63;
    const int wm = wave >> 1, wn = wave & 1;
    const int m0 = blockIdx.y * 128, n0 = blockIdx.x * 128;
    const int quad = lane >> 4, c = lane & 15;

    const int srow = t >> 1, skh = t & 1;
    const int sslot = (srow >> 4) * 64 + (skh * 2) * 16 + (srow & 15);

    v4f acc[4][4];
#pragma unroll
    for (int i = 0; i < 4; ++i)
#pragma unroll
        for (int j = 0; j < 4; ++j) acc[i][j] = (v4f){0.f, 0.f, 0.f, 0.f};

    const unsigned short* pa_u = (const unsigned short*)Av + (size_t)(m0 + srow) * K + skh * 16;
    const float*          pa_f = (const float*)Av          + (size_t)(m0 + srow) * K + skh * 16;
    const float*          pb   = B                          + (size_t)(n0 + srow) * K + skh * 16;

    const int fbase = (quad * 16 + c) * 8;

    for (int k0 = 0; k0 < K; k0 += 32) {
        unsigned short a16[16], b16[16];
        if (A_BF16) {
            uint4 r0 = *(const uint4*)(pa_u + k0);
            uint4 r1 = *(const uint4*)(pa_u + k0 + 8);
            *(uint4*)&a16[0] = r0; *(uint4*)&a16[8] = r1;
        } else {
            float4 f0 = *(const float4*)(pa_f + k0);
            float4 f1 = *(const float4*)(pa_f + k0 + 4);
            float4 f2 = *(const float4*)(pa_f + k0 + 8);
            float4 f3 = *(const float4*)(pa_f + k0 + 12);
            a16[0] = f2bf_rh(f0.x); a16[1] = f2bf_rh(f0.y); a16[2] = f2bf_rh(f0.z); a16[3] = f2bf_rh(f0.w);
            a16[4] = f2bf_rh(f1.x); a16[5] = f2bf_rh(f1.y); a16[6] = f2bf_rh(f1.z); a16[7] = f2bf_rh(f1.w);
            a16[8] = f2bf_rh(f2.x); a16[9] = f2bf_rh(f2.y); a16[10] = f2bf_rh(f2.z); a16[11] = f2bf_rh(f2.w);
            a16[12] = f2bf_rh(f3.x); a16[13] = f2bf_rh(f3.y); a16[14] = f2bf_rh(f3.z); a16[15] = f2bf_rh(f3.w);
        }
        {
            float4 g0 = *(const float4*)(pb + k0);
            float4 g1 = *(const float4*)(pb + k0 + 4);
            float4 g2 = *(const float4*)(pb + k0 + 8);
            float4 g3 = *(const float4*)(pb + k0 + 12);
            b16[0] = f2bf_rh(g0.x); b16[1] = f2bf_rh(g0.y); b16[2] = f2bf_rh(g0.z); b16[3] = f2bf_rh(g0.w);
            b16[4] = f2bf_rh(g1.x); b16[5] = f2bf_rh(g1.y); b16[6] = f2bf_rh(g1.z); b16[7] = f2bf_rh(g1.w);
            b16[8] = f2bf_rh(g2.x); b16[9] = f2bf_rh(g2.y); b16[10] = f2bf_rh(g2.z); b16[11] = f2bf_rh(g2.w);
            b16[12] = f2bf_rh(g3.x); b16[13] = f2bf_rh(g3.y); b16[14] = f2bf_rh(g3.z); b16[15] = f2bf_rh(g3.w);
        }
        __syncthreads();
        *(uint4*)&Al[sslot * 8]        = *(uint4*)&a16[0];
        *(uint4*)&Al[(sslot + 16) * 8] = *(uint4*)&a16[8];
        *(uint4*)&Bl[sslot * 8]        = *(uint4*)&b16[0];
        *(uint4*)&Bl[(sslot + 16) * 8] = *(uint4*)&b16[8];
        __syncthreads();

        v8s af[4], bf[4];
#pragma unroll
        for (int ms = 0; ms < 4; ++ms)
            af[ms] = *(const v8s*)&Al[(wm * 4 + ms) * 512 + fbase];
#pragma unroll
        for (int ns = 0; ns < 4; ++ns)
            bf[ns] = *(const v8s*)&Bl[(wn * 4 + ns) * 512 + fbase];
#pragma unroll
        for (int ms = 0; ms < 4; ++ms)
#pragma unroll
            for (int ns = 0; ns < 4; ++ns)
                acc[ms][ns] = __builtin_amdgcn_mfma_f32_16x16x32_bf16(
                    af[ms], bf[ns], acc[ms][ns], 0, 0, 0);
    }

#pragma unroll
    for (int ms = 0; ms < 4; ++ms) {
        const int row0 = m0 + wm * 64 + ms * 16 + quad * 4;
#pragma unroll
        for (int ns = 0; ns < 4; ++ns) {
            const int colbase = n0 + wn * 64 + ns * 16;
            float bn = (EPI == 2) ? bias[colbase + c] : bias[colbase + c];
            float v0 = acc[ms][ns][0] + bn;
            float v1 = acc[ms][ns][1] + bn;
            float v2 = acc[ms][ns][2] + bn;
            float v3 = acc[ms][ns][3] + bn;
            if (EPI == 2) {
                float* pc = Cf + (size_t)row0 * Nc + colbase + c;
                pc[0] = v0; pc[(size_t)Nc] = v1;
                pc[(size_t)2 * Nc] = v2; pc[(size_t)3 * Nc] = v3;
            } else {
                const int hh = colbase / 192;
                const int eb = colbase - hh * 192;
                const int bb = row0 >> 11, tok0 = row0 & 2047;
                const int bhh = bb * 16 + hh;
                if (eb >= 128) {
                    ushort4 pk;
                    pk.x = f2bf(v0); pk.y = f2bf(v1); pk.z = f2bf(v2); pk.w = f2bf(v3);
                    *(ushort4*)(VTb + ((size_t)bhh * 64 + (eb - 128) + c) * 2048 + tok0) = pk;
                } else {
                    const bool isq = (eb >= 64);
                    const float s = isq ? SCALE2 : 1.f;
                    unsigned short* dst = isq ? Qb : Kb;
                    const int e = (isq ? eb - 64 : eb) + c;
                    const size_t base = ((size_t)bhh * 2048 + tok0) * 64 + e;
                    dst[base]       = f2bf(v0 * s);
                    dst[base + 64]  = f2bf(v1 * s);
                    dst[base + 128] = f2bf(v2 * s);
                    dst[base + 192] = f2bf(v3 * s);
                }
            }
        }
    }
}

// ---------------- barrier-free MFMA flash attention, constant-m softmax -----------
// grid 512 x 256thr. bh = blockIdx&63 (XCD-grouped), bq = blockIdx>>6 (0..7).
// Wave w handles 64 queries of qt in {bq, 15-bq, 16+bq, 31-bq} (uniform 66 kt/block).
// Q pre-scaled by 0.125*log2e; P = exp2(s) raw (|s|<=46 hard bound); l via ones-MFMA.
// K/V fragments read directly from global (L2); Ps per-wave LDS, DOUBLE-BUFFERED
// per kt (no WAR between PV(kt) reads and QK(kt+1) stores); V prefetched at
// iteration top so its L2 latency hides under the QK+softmax phase.
#define ATTS 72

__global__ __launch_bounds__(256, 2) void attn_mfma(
    const unsigned short* __restrict__ Kbuf,  // [64][2048][64]
    const unsigned short* __restrict__ Qbuf,  // [64][2048][64] (scaled)
    const unsigned short* __restrict__ VT,    // [64][64][2048]
    unsigned short* __restrict__ sa)          // [8192][1024]
{
    __shared__ __align__(16) unsigned short Ps[4][2][64 * ATTS];

    const int t = threadIdx.x, w = t >> 6, lane = t & 63;
    const int quad = lane >> 4, c = lane & 15;
    const int bh = blockIdx.x & 63, bq = blockIdx.x >> 6;
    const int b = bh >> 4, hh = bh & 15;
    const int qt = (w == 0) ? bq : (w == 1) ? (15 - bq) : (w == 2) ? (16 + bq) : (31 - bq);
    const int qw = qt * 64;
    const size_t gbase = (size_t)bh * (2048 * 64);

    const int rs  = c & 3;
    const int rc0 = (quad ^ rs) * 8, rc1 = 32 + rc0;
    unsigned short* PsW0 = &Ps[w][0][0];
    unsigned short* PsW1 = &Ps[w][1][0];

    v8s qf[4][2];
#pragma unroll
    for (int qs = 0; qs < 4; ++qs) {
        const unsigned short* qp = Qbuf + gbase + (size_t)(qw + qs * 16 + c) * 64 + quad * 8;
        qf[qs][0] = *(const v8s*)qp;
        qf[qs][1] = *(const v8s*)(qp + 32);
    }
    v4f oacc[4][4], lacc[4];
#pragma unroll
    for (int qs = 0; qs < 4; ++qs) {
        lacc[qs] = (v4f){0.f, 0.f, 0.f, 0.f};
#pragma unroll
        for (int dn = 0; dn < 4; ++dn) oacc[qs][dn] = (v4f){0.f, 0.f, 0.f, 0.f};
    }
    const short oneb = (short)0x3F80;  // bf16 1.0
    const v8s ones = {oneb, oneb, oneb, oneb, oneb, oneb, oneb, oneb};

    const int nkt = qt + 1;
    for (int kt = 0; kt < nkt; ++kt) {
        const int kbase = kt * 64;
        const bool diag = (kt == nkt - 1);   // wave-uniform; kbase == qw on this kt
        unsigned short* PsW = (kt & 1) ? PsW1 : PsW0;

        // ---- V prefetch: issued before K loads; vmcnt FIFO => arrived by PV ----
        v8s vf[4][2];
#pragma unroll
        for (int dn = 0; dn < 4; ++dn) {
            const unsigned short* vp =
                VT + gbase + (size_t)(dn * 16 + c) * 2048 + kbase + quad * 8;
            vf[dn][0] = *(const v8s*)vp;
            vf[dn][1] = *(const v8s*)(vp + 32);
        }

        // ---- S = Q K^T, P = exp2(S) streamed straight into Ps (A-layout via swizzle)
#pragma unroll
        for (int kn = 0; kn < 4; ++kn) {
            const unsigned short* kp =
                Kbuf + gbase + (size_t)(kbase + kn * 16 + c) * 64 + quad * 8;
            v8s kf0 = *(const v8s*)kp;
            v8s kf1 = *(const v8s*)(kp + 32);
#pragma unroll
            for (int qs = 0; qs < 4; ++qs) {
                v4f s = (v4f){0.f, 0.f, 0.f, 0.f};
                s = __builtin_amdgcn_mfma_f32_16x16x32_bf16(qf[qs][0], kf0, s, 0, 0, 0);
                s = __builtin_amdgcn_mfma_f32_16x16x32_bf16(qf[qs][1], kf1, s, 0, 0, 0);
                if (diag) {
#pragma unroll
                    for (int r = 0; r < 4; ++r)
                        if (kn * 16 + c > qs * 16 + quad * 4 + r) s[r] = -1e30f;
                }
#pragma unroll
                for (int r = 0; r < 4; ++r) {
                    const float p = fast_exp2(s[r]);
                    PsW[(qs * 16 + quad * 4 + r) * ATTS +
                        (((2 * kn + (c >> 3)) ^ r) * 8) + (c & 7)] = f2bf_rh(p);
                }
            }
        }
        // ---- P fragments (A-layout), then O += P V and l += P @ ones
        v8s pa[4][2];
#pragma unroll
        for (int qs = 0; qs < 4; ++qs) {
            pa[qs][0] = *(const v8s*)&PsW[(qs * 16 + c) * ATTS + rc0];
            pa[qs][1] = *(const v8s*)&PsW[(qs * 16 + c) * ATTS + rc1];
        }
#pragma unroll
        for (int dn = 0; dn < 4; ++dn) {
#pragma unroll
            for (int qs = 0; qs < 4; ++qs) {
                oacc[qs][dn] = __builtin_amdgcn_mfma_f32_16x16x32_bf16(pa[qs][0], vf[dn][0], oacc[qs][dn], 0, 0, 0);
                oacc[qs][dn] = __builtin_amdgcn_mfma_f32_16x16x32_bf16(pa[qs][1], vf[dn][1], oacc[qs][dn], 0, 0, 0);
            }
        }
#pragma unroll
        for (int qs = 0; qs < 4; ++qs) {
            lacc[qs] = __builtin_amdgcn_mfma_f32_16x16x32_bf16(pa[qs][0], ones, lacc[qs], 0, 0, 0);
            lacc[qs] = __builtin_amdgcn_mfma_f32_16x16x32_bf16(pa[qs][1], ones, lacc[qs], 0, 0, 0);
        }
    }

    // epilogue: sa[b, qw + qs*16 + quad*4 + r, hh*64 + dn*16 + c]
#pragma unroll
    for (int qs = 0; qs < 4; ++qs) {
        float inv[4];
#pragma unroll
        for (int r = 0; r < 4; ++r) inv[r] = 1.f / lacc[qs][r];
        const size_t obase =
            ((size_t)(b * 2048 + qw + qs * 16 + quad * 4)) * DMODEL + hh * 64;
#pragma unroll
        for (int dn = 0; dn < 4; ++dn)
#pragma unroll
            for (int r = 0; r < 4; ++r)
                sa[obase + (size_t)r * DMODEL + dn * 16 + c] = f2bf(oacc[qs][dn][r] * inv[r]);
    }
}

extern "C" void kernel_launch(void* const* d_in, const int* in_sizes, int n_in,
                              void* d_out, int out_size, void* d_ws, size_t ws_size,
                              hipStream_t stream) {
    const float* x     = (const float*)d_in[0];
    const float* Wkqv  = (const float*)d_in[1];
    const float* bkqv  = (const float*)d_in[2];
    const float* Wproj = (const float*)d_in[3];
    const float* bproj = (const float*)d_in[4];
    float* out = (float*)d_out;

    unsigned short* Kb = (unsigned short*)d_ws;        // [64][2048][64]
    unsigned short* Qb = Kb + (size_t)8388608;         // [64][2048][64]
    unsigned short* VT = Qb + (size_t)8388608;         // [64][64][2048]
    unsigned short* sa = VT + (size_t)8388608;         // [8192][1024]

    const bool fast = ws_size >= 75497472ull;          // 72 MiB
    if (fast) {
        unsigned short* xb  = sa;                      // xb dead before attn writes sa
        unsigned short* wkb = (unsigned short*)d_ws + (size_t)33554432;
        unsigned short* wpb = wkb + (size_t)3145728;
        cvt_bf16<<<12288, 256, 0, stream>>>(x, Wkqv, Wproj, xb, wkb, wpb);
        gemm_lds<1><<<dim3(12, 32), 512, 0, stream>>>(
            xb, wkb, bkqv, nullptr, Kb, Qb, VT, 8192, 3072, 1024);
        attn_mfma<<<512, 256, 0, stream>>>(Kb, Qb, VT, sa);
        gemm_lds<2><<<dim3(4, 32), 512, 0, stream>>>(
            sa, wpb, bproj, out, nullptr, nullptr, nullptr, 8192, 1024, 1024);
    } else {
        gemm_mfma<false, 1><<<dim3(24, 64), 256, 0, stream>>>(
            x, Wkqv, bkqv, nullptr, Kb, Qb, VT, 8192, 3072, 1024);
        attn_mfma<<<512, 256, 0, stream>>>(Kb, Qb, VT, sa);
        gemm_mfma<true, 2><<<dim3(8, 64), 256, 0, stream>>>(
            sa, Wproj, bproj, out, nullptr, nullptr, nullptr, 8192, 1024, 1024);
    }
}

// Round 5
// 291.594 us; speedup vs baseline: 1.1449x; 1.0477x over previous
//
#include <hip/hip_runtime.h>
#include <hip/hip_bf16.h>

// CausalSelfAttention: B=4, N=2048, D=1024, H=16, HD=64. fp32 in / fp32 out.
// R12: attn -> balanced split-K. Constant-m softmax => partials (O, l) just add.
//      Per-wave kt counts {16,16,17,17} for every block (was {bq+1..32-bq}, makespan
//      32-bq): waves 0/1 own a short complete q-tile + the tail keys [17,nkt) of a
//      long q-tile; waves 2/3 own head keys [0,17) of the long tiles; merge via LDS
//      (stride-81, conflict-free) + one convergent __syncthreads. Ps back to single
//      buffer (R11 dbuf was ~neutral); LDS 78.3KB -> still 2 blocks/CU.
//      gemm/cvt unchanged from R10/R11.
// ws: Kb/Qb/VT/sa 4x16.78MB = 64MiB; fast path adds wkb+wpb -> 72MiB; xb overlaps sa.

#define NSEQ 2048
#define NHEAD 16
#define DMODEL 1024
#define SCALE2 0.18033688011112042f  // 0.125 * log2(e)

typedef __attribute__((ext_vector_type(8))) short v8s;  // 8 bf16 = 4 VGPRs
typedef __attribute__((ext_vector_type(4))) float v4f;  // MFMA acc

__device__ __forceinline__ float bf2f(unsigned short u) {
    union { unsigned int i; float f; } v;
    v.i = ((unsigned int)u) << 16;
    return v.f;
}
__device__ __forceinline__ unsigned short f2bf(float f) {  // RNE
    unsigned int x = __float_as_uint(f);
    return (unsigned short)((x + 0x7fffu + ((x >> 16) & 1u)) >> 16);
}
__device__ __forceinline__ unsigned short f2bf_rh(float f) {  // round-half-up
    return (unsigned short)((__float_as_uint(f) + 0x8000u) >> 16);
}
__device__ __forceinline__ float fast_exp2(float x) {
#if __has_builtin(__builtin_amdgcn_exp2f)
    return __builtin_amdgcn_exp2f(x);
#else
    return __expf(x * 0.69314718056f);
#endif
}
__device__ __forceinline__ void gld_lds16(const unsigned short* g, unsigned short* l) {
    __builtin_amdgcn_global_load_lds(
        (const __attribute__((address_space(1))) void*)g,
        (__attribute__((address_space(3))) void*)l, 16, 0, 0);
}

// ---------------- cvt: fp32 -> bf16 for x, Wkqv (class-major permute), Wproj -------
// Wkqv in rows h*192 + cls*64 + e -> wkb rows cls*1024 + h*64 + e.
__global__ __launch_bounds__(256) void cvt_bf16(
    const float* __restrict__ x, const float* __restrict__ wk, const float* __restrict__ wp,
    unsigned short* __restrict__ xb, unsigned short* __restrict__ wkb,
    unsigned short* __restrict__ wpb)
{
    const int i = blockIdx.x * 256 + threadIdx.x;   // quad index, 3145728 total
    const float* s; unsigned short* d; int o;
    if (i < 2097152)      { s = x;  d = xb;  o = i; }
    else if (i < 2883584) {
        s = wk; d = wkb;
        const int oi  = i - 2097152;          // 0..786431
        const int row = oi >> 8, cq = oi & 255;
        const int h   = row / 192;
        const int rem = row - h * 192;
        const int cls = rem >> 6, e = rem & 63;
        float4 f = ((const float4*)s)[oi];
        ushort4 u;
        u.x = f2bf(f.x); u.y = f2bf(f.y); u.z = f2bf(f.z); u.w = f2bf(f.w);
        ((ushort4*)d)[(((cls << 10) + (h << 6) + e) << 8) + cq] = u;
        return;
    }
    else                  { s = wp; d = wpb; o = i - 2883584; }
    float4 f = ((const float4*)s)[o];
    ushort4 u;
    u.x = f2bf(f.x); u.y = f2bf(f.y); u.z = f2bf(f.z); u.w = f2bf(f.w);
    ((ushort4*)d)[o] = u;
}

// ---------------- fast MFMA GEMM: 256x256 tile, 8-phase-style pipelined staging ----
// C[M,Nc] = A[M,K] @ B[Nc,K]^T + bias. 512 thr = 8 waves (2Mx4N), per-wave 128x64.
// 4-slot LDS ring (A 16KB + B 16KB per slot = 128 KiB). Tile t+3 staged while
// computing tile t; vmcnt(8) once per K-step keeps 8 loads in flight across
// barriers. Requires gridDim.y == 32 and K >= 96 (nt >= 3).
// EPI=1: B is class-major-permuted kqv weights; split-write Kb/Qb(scaled)/VT.
// EPI=2: plain fp32 C.
template <int EPI>
__global__ __launch_bounds__(512, 2) void gemm_lds(
    const unsigned short* __restrict__ A, const unsigned short* __restrict__ B,
    const float* __restrict__ bias,
    float* __restrict__ Cf,
    unsigned short* __restrict__ Kb, unsigned short* __restrict__ Qb,
    unsigned short* __restrict__ VTb,
    int M, int Nc, int K)
{
    __shared__ __align__(16) unsigned short Al[4][8192];   // 4 slots x 256rows x 32k
    __shared__ __align__(16) unsigned short Bl[4][8192];

    const int t = threadIdx.x, wave = t >> 6, lane = t & 63;
    const int wm = wave >> 2, wn = wave & 3;               // 2 x 4 wave grid

    // XCD-chunked bijective swizzle (gridDim.y == 32 -> 4 m-rows per XCD chunk):
    // xcd owns 4 consecutive by; within chunk, by fastest -> B-tile (512KB) reused
    // 4x while 2MB A-panel stays hot in per-XCD L2.
    const int lin = blockIdx.y * gridDim.x + blockIdx.x;
    const int xcd = lin & 7, pos = lin >> 3;
    const int by  = (xcd << 2) + (pos & 3);
    const int bx  = pos >> 2;
    const int m0 = by * 256, n0 = bx * 256;
    const int quad = lane >> 4, c = lane & 15;

    // staging: wave w loads 16-row groups {2w, 2w+1} of both A and B.
    const int g0 = wave * 2, g1 = wave * 2 + 1;
    const int r15 = lane & 15, kg = (lane >> 4) & 3;
    const unsigned short* sA0 = A + (size_t)(m0 + g0 * 16 + r15) * K + kg * 8;
    const unsigned short* sA1 = A + (size_t)(m0 + g1 * 16 + r15) * K + kg * 8;
    const unsigned short* sB0 = B + (size_t)(n0 + g0 * 16 + r15) * K + kg * 8;
    const unsigned short* sB1 = B + (size_t)(n0 + g1 * 16 + r15) * K + kg * 8;

    v4f acc[8][4];
#pragma unroll
    for (int i = 0; i < 8; ++i)
#pragma unroll
        for (int j = 0; j < 4; ++j) acc[i][j] = (v4f){0.f, 0.f, 0.f, 0.f};

    const int fbase = (quad * 16 + c) * 8;
    const int nt = K >> 5;   // 32-wide K tiles (K=1024 -> 32)

    auto stageA = [&](int sl, int tt) {
        const int o = tt << 5;
        unsigned short* la = &Al[sl][0];
        gld_lds16(sA0 + o, la + g0 * 512);
        gld_lds16(sA1 + o, la + g1 * 512);
    };
    auto stageB = [&](int sl, int tt) {
        const int o = tt << 5;
        unsigned short* lb = &Bl[sl][0];
        gld_lds16(sB0 + o, lb + g0 * 512);
        gld_lds16(sB1 + o, lb + g1 * 512);
    };

    // prologue: tiles 0,1,2 staged (12 loads); wait tile 0 (leave 8 in flight)
    stageA(0, 0); stageB(0, 0);
    stageA(1, 1); stageB(1, 1);
    stageA(2, 2); stageB(2, 2);
    asm volatile("s_waitcnt vmcnt(8)" ::: "memory");
    __builtin_amdgcn_s_barrier();

    for (int tt = 0; tt < nt; ++tt) {
        const int sl  = tt & 3;
        const int sl3 = (tt + 3) & 3;
        const bool pf = (tt + 3 < nt);

        // ---- phase 1: B frags + A frags ms0-3; stage A(t+3); MFMA quadrant 1 ----
        v8s bfr[4], af[4];
#pragma unroll
        for (int ns = 0; ns < 4; ++ns)
            bfr[ns] = *(const v8s*)&Bl[sl][(wn * 4 + ns) * 512 + fbase];
#pragma unroll
        for (int ms = 0; ms < 4; ++ms)
            af[ms] = *(const v8s*)&Al[sl][(wm * 8 + ms) * 512 + fbase];
        if (pf) stageA(sl3, tt + 3);
        __builtin_amdgcn_s_barrier();
        asm volatile("s_waitcnt lgkmcnt(0)" ::: "memory");
        __builtin_amdgcn_s_setprio(1);
#pragma unroll
        for (int ms = 0; ms < 4; ++ms)
#pragma unroll
            for (int ns = 0; ns < 4; ++ns)
                acc[ms][ns] = __builtin_amdgcn_mfma_f32_16x16x32_bf16(
                    af[ms], bfr[ns], acc[ms][ns], 0, 0, 0);
        __builtin_amdgcn_s_setprio(0);
        __builtin_amdgcn_s_barrier();

        // ---- phase 2: A frags ms4-7; stage B(t+3); MFMA quadrant 2 --------------
        v8s af2[4];
#pragma unroll
        for (int ms = 0; ms < 4; ++ms)
            af2[ms] = *(const v8s*)&Al[sl][(wm * 8 + 4 + ms) * 512 + fbase];
        if (pf) stageB(sl3, tt + 3);
        __builtin_amdgcn_s_barrier();
        asm volatile("s_waitcnt lgkmcnt(0)" ::: "memory");
        __builtin_amdgcn_s_setprio(1);
#pragma unroll
        for (int ms = 0; ms < 4; ++ms)
#pragma unroll
            for (int ns = 0; ns < 4; ++ns)
                acc[4 + ms][ns] = __builtin_amdgcn_mfma_f32_16x16x32_bf16(
                    af2[ms], bfr[ns], acc[4 + ms][ns], 0, 0, 0);
        __builtin_amdgcn_s_setprio(0);
        // counted wait: retire tile tt+1's 4 loads; tiles tt+2, tt+3 stay in flight
        if (pf)                   { asm volatile("s_waitcnt vmcnt(8)" ::: "memory"); }
        else if (tt + 2 < nt)     { asm volatile("s_waitcnt vmcnt(4)" ::: "memory"); }
        else                      { asm volatile("s_waitcnt vmcnt(0)" ::: "memory"); }
        __builtin_amdgcn_s_barrier();
    }

#pragma unroll
    for (int ms = 0; ms < 8; ++ms) {
        const int row0 = m0 + wm * 128 + ms * 16 + quad * 4;
#pragma unroll
        for (int ns = 0; ns < 4; ++ns) {
            const int colbase = n0 + wn * 64 + ns * 16;   // wave-uniform, 16-aligned
            float bn, scl = 1.f;
            if (EPI == 2) {
                bn = bias[colbase + c];
            } else {
                const int cls = colbase >> 10;
                const int wi  = colbase & 1023;
                const int h   = wi >> 6, e0 = wi & 63;
                bn = bias[h * 192 + cls * 64 + e0 + c];
                if (cls == 1) scl = SCALE2;
            }
            float v0 = (acc[ms][ns][0] + bn) * scl;
            float v1 = (acc[ms][ns][1] + bn) * scl;
            float v2 = (acc[ms][ns][2] + bn) * scl;
            float v3 = (acc[ms][ns][3] + bn) * scl;
            if (EPI == 2) {
                float* pc = Cf + (size_t)row0 * Nc + colbase + c;
                pc[0] = v0; pc[(size_t)Nc] = v1;
                pc[(size_t)2 * Nc] = v2; pc[(size_t)3 * Nc] = v3;
            } else {
                const int cls = colbase >> 10;
                const int wi  = colbase & 1023;
                const int h   = wi >> 6, e = (wi & 63) + c;
                const int bb  = row0 >> 11, tok0 = row0 & 2047;
                const int bhh = bb * 16 + h;
                if (cls == 2) {            // V -> transposed [bh][dim][tok]
                    ushort4 pk;
                    pk.x = f2bf(v0); pk.y = f2bf(v1); pk.z = f2bf(v2); pk.w = f2bf(v3);
                    *(ushort4*)(VTb + ((size_t)bhh * 64 + e) * 2048 + tok0) = pk;
                } else {                   // K or Q -> [bh][tok][dim]
                    unsigned short* dst = (cls == 0) ? Kb : Qb;
                    const size_t base = ((size_t)bhh * 2048 + tok0) * 64 + e;
                    dst[base]       = f2bf(v0);
                    dst[base + 64]  = f2bf(v1);
                    dst[base + 128] = f2bf(v2);
                    dst[base + 192] = f2bf(v3);
                }
            }
        }
    }
}

// ---------------- fallback GEMM (fp32 sources, VGPR-roundtrip staging) -------------
// EPI=1 uses ORIGINAL (unpermuted) Wkqv col mapping h*192+e; scales Q by SCALE2.
template <bool A_BF16, int EPI>
__global__ __launch_bounds__(256) void gemm_mfma(
    const void* __restrict__ Av, const float* __restrict__ B,
    const float* __restrict__ bias,
    float* __restrict__ Cf,
    unsigned short* __restrict__ Kb, unsigned short* __restrict__ Qb,
    unsigned short* __restrict__ VTb,
    int M, int Nc, int K)
{
    __shared__ __align__(16) unsigned short Al[512 * 8];
    __shared__ __align__(16) unsigned short Bl[512 * 8];

    const int t = threadIdx.x;
    const int wave = t >> 6, lane = t & 63;
    const int wm = wave >> 1, wn = wave & 1;
    const int m0 = blockIdx.y * 128, n0 = blockIdx.x * 128;
    const int quad = lane >> 4, c = lane & 15;

    const int srow = t >> 1, skh = t & 1;
    const int sslot = (srow >> 4) * 64 + (skh * 2) * 16 + (srow & 15);

    v4f acc[4][4];
#pragma unroll
    for (int i = 0; i < 4; ++i)
#pragma unroll
        for (int j = 0; j < 4; ++j) acc[i][j] = (v4f){0.f, 0.f, 0.f, 0.f};

    const unsigned short* pa_u = (const unsigned short*)Av + (size_t)(m0 + srow) * K + skh * 16;
    const float*          pa_f = (const float*)Av          + (size_t)(m0 + srow) * K + skh * 16;
    const float*          pb   = B                          + (size_t)(n0 + srow) * K + skh * 16;

    const int fbase = (quad * 16 + c) * 8;

    for (int k0 = 0; k0 < K; k0 += 32) {
        unsigned short a16[16], b16[16];
        if (A_BF16) {
            uint4 r0 = *(const uint4*)(pa_u + k0);
            uint4 r1 = *(const uint4*)(pa_u + k0 + 8);
            *(uint4*)&a16[0] = r0; *(uint4*)&a16[8] = r1;
        } else {
            float4 f0 = *(const float4*)(pa_f + k0);
            float4 f1 = *(const float4*)(pa_f + k0 + 4);
            float4 f2 = *(const float4*)(pa_f + k0 + 8);
            float4 f3 = *(const float4*)(pa_f + k0 + 12);
            a16[0] = f2bf_rh(f0.x); a16[1] = f2bf_rh(f0.y); a16[2] = f2bf_rh(f0.z); a16[3] = f2bf_rh(f0.w);
            a16[4] = f2bf_rh(f1.x); a16[5] = f2bf_rh(f1.y); a16[6] = f2bf_rh(f1.z); a16[7] = f2bf_rh(f1.w);
            a16[8] = f2bf_rh(f2.x); a16[9] = f2bf_rh(f2.y); a16[10] = f2bf_rh(f2.z); a16[11] = f2bf_rh(f2.w);
            a16[12] = f2bf_rh(f3.x); a16[13] = f2bf_rh(f3.y); a16[14] = f2bf_rh(f3.z); a16[15] = f2bf_rh(f3.w);
        }
        {
            float4 g0 = *(const float4*)(pb + k0);
            float4 g1 = *(const float4*)(pb + k0 + 4);
            float4 g2 = *(const float4*)(pb + k0 + 8);
            float4 g3 = *(const float4*)(pb + k0 + 12);
            b16[0] = f2bf_rh(g0.x); b16[1] = f2bf_rh(g0.y); b16[2] = f2bf_rh(g0.z); b16[3] = f2bf_rh(g0.w);
            b16[4] = f2bf_rh(g1.x); b16[5] = f2bf_rh(g1.y); b16[6] = f2bf_rh(g1.z); b16[7] = f2bf_rh(g1.w);
            b16[8] = f2bf_rh(g2.x); b16[9] = f2bf_rh(g2.y); b16[10] = f2bf_rh(g2.z); b16[11] = f2bf_rh(g2.w);
            b16[12] = f2bf_rh(g3.x); b16[13] = f2bf_rh(g3.y); b16[14] = f2bf_rh(g3.z); b16[15] = f2bf_rh(g3.w);
        }
        __syncthreads();
        *(uint4*)&Al[sslot * 8]        = *(uint4*)&a16[0];
        *(uint4*)&Al[(sslot + 16) * 8] = *(uint4*)&a16[8];
        *(uint4*)&Bl[sslot * 8]        = *(uint4*)&b16[0];
        *(uint4*)&Bl[(sslot + 16) * 8] = *(uint4*)&b16[8];
        __syncthreads();

        v8s af[4], bf[4];
#pragma unroll
        for (int ms = 0; ms < 4; ++ms)
            af[ms] = *(const v8s*)&Al[(wm * 4 + ms) * 512 + fbase];
#pragma unroll
        for (int ns = 0; ns < 4; ++ns)
            bf[ns] = *(const v8s*)&Bl[(wn * 4 + ns) * 512 + fbase];
#pragma unroll
        for (int ms = 0; ms < 4; ++ms)
#pragma unroll
            for (int ns = 0; ns < 4; ++ns)
                acc[ms][ns] = __builtin_amdgcn_mfma_f32_16x16x32_bf16(
                    af[ms], bf[ns], acc[ms][ns], 0, 0, 0);
    }

#pragma unroll
    for (int ms = 0; ms < 4; ++ms) {
        const int row0 = m0 + wm * 64 + ms * 16 + quad * 4;
#pragma unroll
        for (int ns = 0; ns < 4; ++ns) {
            const int colbase = n0 + wn * 64 + ns * 16;
            float bn = (EPI == 2) ? bias[colbase + c] : bias[colbase + c];
            float v0 = acc[ms][ns][0] + bn;
            float v1 = acc[ms][ns][1] + bn;
            float v2 = acc[ms][ns][2] + bn;
            float v3 = acc[ms][ns][3] + bn;
            if (EPI == 2) {
                float* pc = Cf + (size_t)row0 * Nc + colbase + c;
                pc[0] = v0; pc[(size_t)Nc] = v1;
                pc[(size_t)2 * Nc] = v2; pc[(size_t)3 * Nc] = v3;
            } else {
                const int hh = colbase / 192;
                const int eb = colbase - hh * 192;
                const int bb = row0 >> 11, tok0 = row0 & 2047;
                const int bhh = bb * 16 + hh;
                if (eb >= 128) {
                    ushort4 pk;
                    pk.x = f2bf(v0); pk.y = f2bf(v1); pk.z = f2bf(v2); pk.w = f2bf(v3);
                    *(ushort4*)(VTb + ((size_t)bhh * 64 + (eb - 128) + c) * 2048 + tok0) = pk;
                } else {
                    const bool isq = (eb >= 64);
                    const float s = isq ? SCALE2 : 1.f;
                    unsigned short* dst = isq ? Qb : Kb;
                    const int e = (isq ? eb - 64 : eb) + c;
                    const size_t base = ((size_t)bhh * 2048 + tok0) * 64 + e;
                    dst[base]       = f2bf(v0 * s);
                    dst[base + 64]  = f2bf(v1 * s);
                    dst[base + 128] = f2bf(v2 * s);
                    dst[base + 192] = f2bf(v3 * s);
                }
            }
        }
    }
}

// ---------------- balanced split-K MFMA flash attention, constant-m softmax -------
// grid 512 x 256thr. bh = blockIdx&63 (XCD-grouped), bq = blockIdx>>6 (0..7).
// Constant-m softmax (P = exp2(s) raw, |s|<=46) => split-K partials just add.
// wave0: qt=bq [0,bq+1) complete + qt=31-bq [17,32-bq) tail      -> 16 kt
// wave1: qt=15-bq [0,16-bq) complete + qt=16+bq [17,17+bq) tail  -> 16 kt
// wave2: qt=16+bq [0,17) head, merges wave1's tail               -> 17 kt
// wave3: qt=31-bq [0,17) head, merges wave0's tail               -> 17 kt
// Merge via Mrg LDS (stride 81 floats -> conflict-free), one convergent barrier.
#define ATTS 72

__global__ __launch_bounds__(256, 2) void attn_mfma(
    const unsigned short* __restrict__ Kbuf,  // [64][2048][64]
    const unsigned short* __restrict__ Qbuf,  // [64][2048][64] (scaled)
    const unsigned short* __restrict__ VT,    // [64][64][2048]
    unsigned short* __restrict__ sa)          // [8192][1024]
{
    __shared__ __align__(16) unsigned short Ps[4][64 * ATTS];   // 36,864 B
    __shared__ __align__(16) float Mrg[2][64][81];              // 41,472 B

    const int t = threadIdx.x, w = t >> 6, lane = t & 63;
    const int quad = lane >> 4, c = lane & 15;
    const int bh = blockIdx.x & 63, bq = blockIdx.x >> 6;
    const int b = bh >> 4, hh = bh & 15;
    const size_t gbase = (size_t)bh * (2048 * 64);

    const int rs  = c & 3;
    const int rc0 = (quad ^ rs) * 8, rc1 = 32 + rc0;
    unsigned short* PsW = &Ps[w][0];

    // balanced segment table (see header comment)
    const int qtA = (w == 0) ? bq : (w == 1) ? (15 - bq) : (w == 2) ? (16 + bq) : (31 - bq);
    const int kA1 = (w == 0) ? (bq + 1) : (w == 1) ? (16 - bq) : 17;
    const int qtB = (w == 0) ? (31 - bq) : (16 + bq);   // waves 0/1 only
    const int kB1 = (w == 0) ? (32 - bq) : (17 + bq);

    v4f oacc[4][4], lacc[4];
    const short oneb = (short)0x3F80;  // bf16 1.0
    const v8s ones = {oneb, oneb, oneb, oneb, oneb, oneb, oneb, oneb};

    auto run_seg = [&](int qt, int k0, int k1) {
        const int qw = qt * 64;
        v8s qf[4][2];
#pragma unroll
        for (int qs = 0; qs < 4; ++qs) {
            const unsigned short* qp =
                Qbuf + gbase + (size_t)(qw + qs * 16 + c) * 64 + quad * 8;
            qf[qs][0] = *(const v8s*)qp;
            qf[qs][1] = *(const v8s*)(qp + 32);
        }
#pragma unroll
        for (int qs = 0; qs < 4; ++qs) {
            lacc[qs] = (v4f){0.f, 0.f, 0.f, 0.f};
#pragma unroll
            for (int dn = 0; dn < 4; ++dn) oacc[qs][dn] = (v4f){0.f, 0.f, 0.f, 0.f};
        }
        for (int kt = k0; kt < k1; ++kt) {
            const int kbase = kt * 64;
            const bool diag = (kt == qt);   // wave-uniform

            // V prefetch (vmcnt FIFO: the K wait also covers V arrival)
            v8s vf[4][2];
#pragma unroll
            for (int dn = 0; dn < 4; ++dn) {
                const unsigned short* vp =
                    VT + gbase + (size_t)(dn * 16 + c) * 2048 + kbase + quad * 8;
                vf[dn][0] = *(const v8s*)vp;
                vf[dn][1] = *(const v8s*)(vp + 32);
            }

            // S = Q K^T, P = exp2(S) streamed into Ps (A-layout via swizzle)
#pragma unroll
            for (int kn = 0; kn < 4; ++kn) {
                const unsigned short* kp =
                    Kbuf + gbase + (size_t)(kbase + kn * 16 + c) * 64 + quad * 8;
                v8s kf0 = *(const v8s*)kp;
                v8s kf1 = *(const v8s*)(kp + 32);
#pragma unroll
                for (int qs = 0; qs < 4; ++qs) {
                    v4f s = (v4f){0.f, 0.f, 0.f, 0.f};
                    s = __builtin_amdgcn_mfma_f32_16x16x32_bf16(qf[qs][0], kf0, s, 0, 0, 0);
                    s = __builtin_amdgcn_mfma_f32_16x16x32_bf16(qf[qs][1], kf1, s, 0, 0, 0);
                    if (diag) {
#pragma unroll
                        for (int r = 0; r < 4; ++r)
                            if (kn * 16 + c > qs * 16 + quad * 4 + r) s[r] = -1e30f;
                    }
#pragma unroll
                    for (int r = 0; r < 4; ++r) {
                        const float p = fast_exp2(s[r]);
                        PsW[(qs * 16 + quad * 4 + r) * ATTS +
                            (((2 * kn + (c >> 3)) ^ r) * 8) + (c & 7)] = f2bf_rh(p);
                    }
                }
            }
            // P fragments (A-layout), then O += P V and l += P @ ones
            v8s pa[4][2];
#pragma unroll
            for (int qs = 0; qs < 4; ++qs) {
                pa[qs][0] = *(const v8s*)&PsW[(qs * 16 + c) * ATTS + rc0];
                pa[qs][1] = *(const v8s*)&PsW[(qs * 16 + c) * ATTS + rc1];
            }
#pragma unroll
            for (int dn = 0; dn < 4; ++dn) {
#pragma unroll
                for (int qs = 0; qs < 4; ++qs) {
                    oacc[qs][dn] = __builtin_amdgcn_mfma_f32_16x16x32_bf16(pa[qs][0], vf[dn][0], oacc[qs][dn], 0, 0, 0);
                    oacc[qs][dn] = __builtin_amdgcn_mfma_f32_16x16x32_bf16(pa[qs][1], vf[dn][1], oacc[qs][dn], 0, 0, 0);
                }
            }
#pragma unroll
            for (int qs = 0; qs < 4; ++qs) {
                lacc[qs] = __builtin_amdgcn_mfma_f32_16x16x32_bf16(pa[qs][0], ones, lacc[qs], 0, 0, 0);
                lacc[qs] = __builtin_amdgcn_mfma_f32_16x16x32_bf16(pa[qs][1], ones, lacc[qs], 0, 0, 0);
            }
        }
    };

    auto store_final = [&](int qt) {
        const int qw = qt * 64;
#pragma unroll
        for (int qs = 0; qs < 4; ++qs) {
            float inv[4];
#pragma unroll
            for (int r = 0; r < 4; ++r) inv[r] = 1.f / lacc[qs][r];
            const size_t obase =
                ((size_t)(b * 2048 + qw + qs * 16 + quad * 4)) * DMODEL + hh * 64;
#pragma unroll
            for (int dn = 0; dn < 4; ++dn)
#pragma unroll
                for (int r = 0; r < 4; ++r)
                    sa[obase + (size_t)r * DMODEL + dn * 16 + c] = f2bf(oacc[qs][dn][r] * inv[r]);
        }
    };

    run_seg(qtA, 0, kA1);
    if (w < 2) {
        store_final(qtA);                 // complete q-tile
        run_seg(qtB, 17, kB1);            // tail of the long q-tile (may be empty)
        float* mg = &Mrg[w][lane][0];
#pragma unroll
        for (int qs = 0; qs < 4; ++qs) {
#pragma unroll
            for (int dn = 0; dn < 4; ++dn)
#pragma unroll
                for (int r = 0; r < 4; ++r) mg[qs * 16 + dn * 4 + r] = oacc[qs][dn][r];
#pragma unroll
            for (int r = 0; r < 4; ++r) mg[64 + qs * 4 + r] = lacc[qs][r];
        }
    }
    __syncthreads();                      // convergent: all 4 waves, exactly once
    if (w >= 2) {
        const float* mg = &Mrg[3 - w][lane][0];   // w=2 <- wave1's tail; w=3 <- wave0's
#pragma unroll
        for (int qs = 0; qs < 4; ++qs) {
#pragma unroll
            for (int dn = 0; dn < 4; ++dn)
#pragma unroll
                for (int r = 0; r < 4; ++r) oacc[qs][dn][r] += mg[qs * 16 + dn * 4 + r];
#pragma unroll
            for (int r = 0; r < 4; ++r) lacc[qs][r] += mg[64 + qs * 4 + r];
        }
        store_final(qtA);
    }
}

extern "C" void kernel_launch(void* const* d_in, const int* in_sizes, int n_in,
                              void* d_out, int out_size, void* d_ws, size_t ws_size,
                              hipStream_t stream) {
    const float* x     = (const float*)d_in[0];
    const float* Wkqv  = (const float*)d_in[1];
    const float* bkqv  = (const float*)d_in[2];
    const float* Wproj = (const float*)d_in[3];
    const float* bproj = (const float*)d_in[4];
    float* out = (float*)d_out;

    unsigned short* Kb = (unsigned short*)d_ws;        // [64][2048][64]
    unsigned short* Qb = Kb + (size_t)8388608;         // [64][2048][64]
    unsigned short* VT = Qb + (size_t)8388608;         // [64][64][2048]
    unsigned short* sa = VT + (size_t)8388608;         // [8192][1024]

    const bool fast = ws_size >= 75497472ull;          // 72 MiB
    if (fast) {
        unsigned short* xb  = sa;                      // xb dead before attn writes sa
        unsigned short* wkb = (unsigned short*)d_ws + (size_t)33554432;
        unsigned short* wpb = wkb + (size_t)3145728;
        cvt_bf16<<<12288, 256, 0, stream>>>(x, Wkqv, Wproj, xb, wkb, wpb);
        gemm_lds<1><<<dim3(12, 32), 512, 0, stream>>>(
            xb, wkb, bkqv, nullptr, Kb, Qb, VT, 8192, 3072, 1024);
        attn_mfma<<<512, 256, 0, stream>>>(Kb, Qb, VT, sa);
        gemm_lds<2><<<dim3(4, 32), 512, 0, stream>>>(
            sa, wpb, bproj, out, nullptr, nullptr, nullptr, 8192, 1024, 1024);
    } else {
        gemm_mfma<false, 1><<<dim3(24, 64), 256, 0, stream>>>(
            x, Wkqv, bkqv, nullptr, Kb, Qb, VT, 8192, 3072, 1024);
        attn_mfma<<<512, 256, 0, stream>>>(Kb, Qb, VT, sa);
        gemm_mfma<true, 2><<<dim3(8, 64), 256, 0, stream>>>(
            sa, Wproj, bproj, out, nullptr, nullptr, nullptr, 8192, 1024, 1024);
    }
}

// Round 6
// 270.560 us; speedup vs baseline: 1.2339x; 1.0777x over previous
//
#include <hip/hip_runtime.h>
#include <hip/hip_bf16.h>

// CausalSelfAttention: B=4, N=2048, D=1024, H=16, HD=64. fp32 in / fp32 out.
// R13: gemm -> 128x256 tile, 8 waves (2Mx4N), acc[4][4], 3-slot LDS ring (72KB ->
//      2 blocks/CU, 16 waves/CU). Grid balance fixed: gemm1 768 blocks (=3x256),
//      gemm2 256 blocks (was 384/128 -> idle CUs). One barrier per K-step:
//      {frag ds_reads, stage t+2 (3 glds), MFMA x16, vmcnt(3), barrier}.
//      XCD swizzle by=(xcd<<3)+(pos&7), bx=pos>>3 (bijective, gridDim.y=64).
//      attn (balanced split-K) / cvt unchanged from R12.
// ws: Kb/Qb/VT/sa 4x16.78MB = 64MiB; fast path adds wkb+wpb -> 72MiB; xb overlaps sa.

#define NSEQ 2048
#define NHEAD 16
#define DMODEL 1024
#define SCALE2 0.18033688011112042f  // 0.125 * log2(e)

typedef __attribute__((ext_vector_type(8))) short v8s;  // 8 bf16 = 4 VGPRs
typedef __attribute__((ext_vector_type(4))) float v4f;  // MFMA acc

__device__ __forceinline__ float bf2f(unsigned short u) {
    union { unsigned int i; float f; } v;
    v.i = ((unsigned int)u) << 16;
    return v.f;
}
__device__ __forceinline__ unsigned short f2bf(float f) {  // RNE
    unsigned int x = __float_as_uint(f);
    return (unsigned short)((x + 0x7fffu + ((x >> 16) & 1u)) >> 16);
}
__device__ __forceinline__ unsigned short f2bf_rh(float f) {  // round-half-up
    return (unsigned short)((__float_as_uint(f) + 0x8000u) >> 16);
}
__device__ __forceinline__ float fast_exp2(float x) {
#if __has_builtin(__builtin_amdgcn_exp2f)
    return __builtin_amdgcn_exp2f(x);
#else
    return __expf(x * 0.69314718056f);
#endif
}
__device__ __forceinline__ void gld_lds16(const unsigned short* g, unsigned short* l) {
    __builtin_amdgcn_global_load_lds(
        (const __attribute__((address_space(1))) void*)g,
        (__attribute__((address_space(3))) void*)l, 16, 0, 0);
}

// ---------------- cvt: fp32 -> bf16 for x, Wkqv (class-major permute), Wproj -------
// Wkqv in rows h*192 + cls*64 + e -> wkb rows cls*1024 + h*64 + e.
__global__ __launch_bounds__(256) void cvt_bf16(
    const float* __restrict__ x, const float* __restrict__ wk, const float* __restrict__ wp,
    unsigned short* __restrict__ xb, unsigned short* __restrict__ wkb,
    unsigned short* __restrict__ wpb)
{
    const int i = blockIdx.x * 256 + threadIdx.x;   // quad index, 3145728 total
    const float* s; unsigned short* d; int o;
    if (i < 2097152)      { s = x;  d = xb;  o = i; }
    else if (i < 2883584) {
        s = wk; d = wkb;
        const int oi  = i - 2097152;          // 0..786431
        const int row = oi >> 8, cq = oi & 255;
        const int h   = row / 192;
        const int rem = row - h * 192;
        const int cls = rem >> 6, e = rem & 63;
        float4 f = ((const float4*)s)[oi];
        ushort4 u;
        u.x = f2bf(f.x); u.y = f2bf(f.y); u.z = f2bf(f.z); u.w = f2bf(f.w);
        ((ushort4*)d)[(((cls << 10) + (h << 6) + e) << 8) + cq] = u;
        return;
    }
    else                  { s = wp; d = wpb; o = i - 2883584; }
    float4 f = ((const float4*)s)[o];
    ushort4 u;
    u.x = f2bf(f.x); u.y = f2bf(f.y); u.z = f2bf(f.z); u.w = f2bf(f.w);
    ((ushort4*)d)[o] = u;
}

// ---------------- fast MFMA GEMM: 128x256 tile, 3-slot ring, 2 blocks/CU ----------
// C[M,Nc] = A[M,K] @ B[Nc,K]^T + bias. 512 thr = 8 waves (2Mx4N), per-wave 64x64.
// LDS ring: 3 slots x (A 8KB + B 16KB) = 72KB -> 2 blocks/CU. Stage tile t+2 while
// computing t; single barrier per K-step; counted vmcnt(3) (never 0 until tail).
// Requires gridDim.y == 64, grid total % 8 == 0, K >= 64.
// EPI=1: B is class-major-permuted kqv weights; split-write Kb/Qb(scaled)/VT.
// EPI=2: plain fp32 C.
template <int EPI>
__global__ __launch_bounds__(512, 4) void gemm_lds(
    const unsigned short* __restrict__ A, const unsigned short* __restrict__ B,
    const float* __restrict__ bias,
    float* __restrict__ Cf,
    unsigned short* __restrict__ Kb, unsigned short* __restrict__ Qb,
    unsigned short* __restrict__ VTb,
    int M, int Nc, int K)
{
    __shared__ __align__(16) unsigned short Al[3][4096];   // 128 rows x 32k
    __shared__ __align__(16) unsigned short Bl[3][8192];   // 256 rows x 32k

    const int t = threadIdx.x, wave = t >> 6, lane = t & 63;
    const int wm = wave >> 2, wn = wave & 3;               // 2 x 4 wave grid

    // XCD-chunked bijective swizzle: per XCD an 8-row A slab (2MB) x all bx;
    // B tile (512KB) reused 8x within the XCD's L2.
    const int lin = blockIdx.y * gridDim.x + blockIdx.x;
    const int xcd = lin & 7, pos = lin >> 3;
    const int by  = (xcd << 3) + (pos & 7);
    const int bx  = pos >> 3;
    const int m0 = by * 128, n0 = bx * 256;
    const int quad = lane >> 4, c = lane & 15;

    // staging: wave w loads A 16-row group w, B groups {2w, 2w+1}.
    const int r15 = lane & 15, kg = (lane >> 4) & 3;
    const int g0 = wave * 2, g1 = wave * 2 + 1;
    const unsigned short* sA  = A + (size_t)(m0 + wave * 16 + r15) * K + kg * 8;
    const unsigned short* sB0 = B + (size_t)(n0 + g0 * 16 + r15) * K + kg * 8;
    const unsigned short* sB1 = B + (size_t)(n0 + g1 * 16 + r15) * K + kg * 8;

    v4f acc[4][4];
#pragma unroll
    for (int i = 0; i < 4; ++i)
#pragma unroll
        for (int j = 0; j < 4; ++j) acc[i][j] = (v4f){0.f, 0.f, 0.f, 0.f};

    const int fbase = (quad * 16 + c) * 8;
    const int nt = K >> 5;   // 32-wide K tiles (K=1024 -> 32)

    auto stage = [&](int sl, int tt) {
        const int o = tt << 5;
        gld_lds16(sA  + o, &Al[sl][wave * 512]);
        gld_lds16(sB0 + o, &Bl[sl][g0 * 512]);
        gld_lds16(sB1 + o, &Bl[sl][g1 * 512]);
    };

    // prologue: tiles 0,1 staged (6 loads/thread); wait tile 0 (leave 3 in flight)
    stage(0, 0);
    stage(1, 1);
    asm volatile("s_waitcnt vmcnt(3)" ::: "memory");
    __builtin_amdgcn_s_barrier();

    int sl = 0;
    for (int tt = 0; tt < nt; ++tt) {
        const int sl2 = (sl == 0) ? 2 : sl - 1;   // (tt+2)%3
        const bool pf = (tt + 2 < nt);

        v8s af[4], bfr[4];
#pragma unroll
        for (int ms = 0; ms < 4; ++ms)
            af[ms] = *(const v8s*)&Al[sl][(wm * 4 + ms) * 512 + fbase];
#pragma unroll
        for (int ns = 0; ns < 4; ++ns)
            bfr[ns] = *(const v8s*)&Bl[sl][(wn * 4 + ns) * 512 + fbase];
        if (pf) stage(sl2, tt + 2);               // overlaps MFMA below

        __builtin_amdgcn_s_setprio(1);
#pragma unroll
        for (int ms = 0; ms < 4; ++ms)
#pragma unroll
            for (int ns = 0; ns < 4; ++ns)
                acc[ms][ns] = __builtin_amdgcn_mfma_f32_16x16x32_bf16(
                    af[ms], bfr[ns], acc[ms][ns], 0, 0, 0);
        __builtin_amdgcn_s_setprio(0);

        // retire tile tt+1's 3 loads; tile tt+2's stay in flight across the barrier
        if (pf) { asm volatile("s_waitcnt vmcnt(3)" ::: "memory"); }
        else    { asm volatile("s_waitcnt vmcnt(0)" ::: "memory"); }
        __builtin_amdgcn_s_barrier();
        sl = (sl == 2) ? 0 : sl + 1;
    }

#pragma unroll
    for (int ms = 0; ms < 4; ++ms) {
        const int row0 = m0 + wm * 64 + ms * 16 + quad * 4;
#pragma unroll
        for (int ns = 0; ns < 4; ++ns) {
            const int colbase = n0 + wn * 64 + ns * 16;   // wave-uniform, 16-aligned
            float bn, scl = 1.f;
            if (EPI == 2) {
                bn = bias[colbase + c];
            } else {
                const int cls = colbase >> 10;
                const int wi  = colbase & 1023;
                const int h   = wi >> 6, e0 = wi & 63;
                bn = bias[h * 192 + cls * 64 + e0 + c];
                if (cls == 1) scl = SCALE2;
            }
            float v0 = (acc[ms][ns][0] + bn) * scl;
            float v1 = (acc[ms][ns][1] + bn) * scl;
            float v2 = (acc[ms][ns][2] + bn) * scl;
            float v3 = (acc[ms][ns][3] + bn) * scl;
            if (EPI == 2) {
                float* pc = Cf + (size_t)row0 * Nc + colbase + c;
                pc[0] = v0; pc[(size_t)Nc] = v1;
                pc[(size_t)2 * Nc] = v2; pc[(size_t)3 * Nc] = v3;
            } else {
                const int cls = colbase >> 10;
                const int wi  = colbase & 1023;
                const int h   = wi >> 6, e = (wi & 63) + c;
                const int bb  = row0 >> 11, tok0 = row0 & 2047;
                const int bhh = bb * 16 + h;
                if (cls == 2) {            // V -> transposed [bh][dim][tok]
                    ushort4 pk;
                    pk.x = f2bf(v0); pk.y = f2bf(v1); pk.z = f2bf(v2); pk.w = f2bf(v3);
                    *(ushort4*)(VTb + ((size_t)bhh * 64 + e) * 2048 + tok0) = pk;
                } else {                   // K or Q -> [bh][tok][dim]
                    unsigned short* dst = (cls == 0) ? Kb : Qb;
                    const size_t base = ((size_t)bhh * 2048 + tok0) * 64 + e;
                    dst[base]       = f2bf(v0);
                    dst[base + 64]  = f2bf(v1);
                    dst[base + 128] = f2bf(v2);
                    dst[base + 192] = f2bf(v3);
                }
            }
        }
    }
}

// ---------------- fallback GEMM (fp32 sources, VGPR-roundtrip staging) -------------
// EPI=1 uses ORIGINAL (unpermuted) Wkqv col mapping h*192+e; scales Q by SCALE2.
template <bool A_BF16, int EPI>
__global__ __launch_bounds__(256) void gemm_mfma(
    const void* __restrict__ Av, const float* __restrict__ B,
    const float* __restrict__ bias,
    float* __restrict__ Cf,
    unsigned short* __restrict__ Kb, unsigned short* __restrict__ Qb,
    unsigned short* __restrict__ VTb,
    int M, int Nc, int K)
{
    __shared__ __align__(16) unsigned short Al[512 * 8];
    __shared__ __align__(16) unsigned short Bl[512 * 8];

    const int t = threadIdx.x;
    const int wave = t >> 6, lane = t & 63;
    const int wm = wave >> 1, wn = wave & 1;
    const int m0 = blockIdx.y * 128, n0 = blockIdx.x * 128;
    const int quad = lane >> 4, c = lane & 15;

    const int srow = t >> 1, skh = t & 1;
    const int sslot = (srow >> 4) * 64 + (skh * 2) * 16 + (srow & 15);

    v4f acc[4][4];
#pragma unroll
    for (int i = 0; i < 4; ++i)
#pragma unroll
        for (int j = 0; j < 4; ++j) acc[i][j] = (v4f){0.f, 0.f, 0.f, 0.f};

    const unsigned short* pa_u = (const unsigned short*)Av + (size_t)(m0 + srow) * K + skh * 16;
    const float*          pa_f = (const float*)Av          + (size_t)(m0 + srow) * K + skh * 16;
    const float*          pb   = B                          + (size_t)(n0 + srow) * K + skh * 16;

    const int fbase = (quad * 16 + c) * 8;

    for (int k0 = 0; k0 < K; k0 += 32) {
        unsigned short a16[16], b16[16];
        if (A_BF16) {
            uint4 r0 = *(const uint4*)(pa_u + k0);
            uint4 r1 = *(const uint4*)(pa_u + k0 + 8);
            *(uint4*)&a16[0] = r0; *(uint4*)&a16[8] = r1;
        } else {
            float4 f0 = *(const float4*)(pa_f + k0);
            float4 f1 = *(const float4*)(pa_f + k0 + 4);
            float4 f2 = *(const float4*)(pa_f + k0 + 8);
            float4 f3 = *(const float4*)(pa_f + k0 + 12);
            a16[0] = f2bf_rh(f0.x); a16[1] = f2bf_rh(f0.y); a16[2] = f2bf_rh(f0.z); a16[3] = f2bf_rh(f0.w);
            a16[4] = f2bf_rh(f1.x); a16[5] = f2bf_rh(f1.y); a16[6] = f2bf_rh(f1.z); a16[7] = f2bf_rh(f1.w);
            a16[8] = f2bf_rh(f2.x); a16[9] = f2bf_rh(f2.y); a16[10] = f2bf_rh(f2.z); a16[11] = f2bf_rh(f2.w);
            a16[12] = f2bf_rh(f3.x); a16[13] = f2bf_rh(f3.y); a16[14] = f2bf_rh(f3.z); a16[15] = f2bf_rh(f3.w);
        }
        {
            float4 g0 = *(const float4*)(pb + k0);
            float4 g1 = *(const float4*)(pb + k0 + 4);
            float4 g2 = *(const float4*)(pb + k0 + 8);
            float4 g3 = *(const float4*)(pb + k0 + 12);
            b16[0] = f2bf_rh(g0.x); b16[1] = f2bf_rh(g0.y); b16[2] = f2bf_rh(g0.z); b16[3] = f2bf_rh(g0.w);
            b16[4] = f2bf_rh(g1.x); b16[5] = f2bf_rh(g1.y); b16[6] = f2bf_rh(g1.z); b16[7] = f2bf_rh(g1.w);
            b16[8] = f2bf_rh(g2.x); b16[9] = f2bf_rh(g2.y); b16[10] = f2bf_rh(g2.z); b16[11] = f2bf_rh(g2.w);
            b16[12] = f2bf_rh(g3.x); b16[13] = f2bf_rh(g3.y); b16[14] = f2bf_rh(g3.z); b16[15] = f2bf_rh(g3.w);
        }
        __syncthreads();
        *(uint4*)&Al[sslot * 8]        = *(uint4*)&a16[0];
        *(uint4*)&Al[(sslot + 16) * 8] = *(uint4*)&a16[8];
        *(uint4*)&Bl[sslot * 8]        = *(uint4*)&b16[0];
        *(uint4*)&Bl[(sslot + 16) * 8] = *(uint4*)&b16[8];
        __syncthreads();

        v8s af[4], bf[4];
#pragma unroll
        for (int ms = 0; ms < 4; ++ms)
            af[ms] = *(const v8s*)&Al[(wm * 4 + ms) * 512 + fbase];
#pragma unroll
        for (int ns = 0; ns < 4; ++ns)
            bf[ns] = *(const v8s*)&Bl[(wn * 4 + ns) * 512 + fbase];
#pragma unroll
        for (int ms = 0; ms < 4; ++ms)
#pragma unroll
            for (int ns = 0; ns < 4; ++ns)
                acc[ms][ns] = __builtin_amdgcn_mfma_f32_16x16x32_bf16(
                    af[ms], bf[ns], acc[ms][ns], 0, 0, 0);
    }

#pragma unroll
    for (int ms = 0; ms < 4; ++ms) {
        const int row0 = m0 + wm * 64 + ms * 16 + quad * 4;
#pragma unroll
        for (int ns = 0; ns < 4; ++ns) {
            const int colbase = n0 + wn * 64 + ns * 16;
            float bn = (EPI == 2) ? bias[colbase + c] : bias[colbase + c];
            float v0 = acc[ms][ns][0] + bn;
            float v1 = acc[ms][ns][1] + bn;
            float v2 = acc[ms][ns][2] + bn;
            float v3 = acc[ms][ns][3] + bn;
            if (EPI == 2) {
                float* pc = Cf + (size_t)row0 * Nc + colbase + c;
                pc[0] = v0; pc[(size_t)Nc] = v1;
                pc[(size_t)2 * Nc] = v2; pc[(size_t)3 * Nc] = v3;
            } else {
                const int hh = colbase / 192;
                const int eb = colbase - hh * 192;
                const int bb = row0 >> 11, tok0 = row0 & 2047;
                const int bhh = bb * 16 + hh;
                if (eb >= 128) {
                    ushort4 pk;
                    pk.x = f2bf(v0); pk.y = f2bf(v1); pk.z = f2bf(v2); pk.w = f2bf(v3);
                    *(ushort4*)(VTb + ((size_t)bhh * 64 + (eb - 128) + c) * 2048 + tok0) = pk;
                } else {
                    const bool isq = (eb >= 64);
                    const float s = isq ? SCALE2 : 1.f;
                    unsigned short* dst = isq ? Qb : Kb;
                    const int e = (isq ? eb - 64 : eb) + c;
                    const size_t base = ((size_t)bhh * 2048 + tok0) * 64 + e;
                    dst[base]       = f2bf(v0 * s);
                    dst[base + 64]  = f2bf(v1 * s);
                    dst[base + 128] = f2bf(v2 * s);
                    dst[base + 192] = f2bf(v3 * s);
                }
            }
        }
    }
}

// ---------------- balanced split-K MFMA flash attention, constant-m softmax -------
// grid 512 x 256thr. bh = blockIdx&63 (XCD-grouped), bq = blockIdx>>6 (0..7).
// Constant-m softmax (P = exp2(s) raw, |s|<=46) => split-K partials just add.
// wave0: qt=bq [0,bq+1) complete + qt=31-bq [17,32-bq) tail      -> 16 kt
// wave1: qt=15-bq [0,16-bq) complete + qt=16+bq [17,17+bq) tail  -> 16 kt
// wave2: qt=16+bq [0,17) head, merges wave1's tail               -> 17 kt
// wave3: qt=31-bq [0,17) head, merges wave0's tail               -> 17 kt
// Merge via Mrg LDS (stride 81 floats -> conflict-free), one convergent barrier.
#define ATTS 72

__global__ __launch_bounds__(256, 2) void attn_mfma(
    const unsigned short* __restrict__ Kbuf,  // [64][2048][64]
    const unsigned short* __restrict__ Qbuf,  // [64][2048][64] (scaled)
    const unsigned short* __restrict__ VT,    // [64][64][2048]
    unsigned short* __restrict__ sa)          // [8192][1024]
{
    __shared__ __align__(16) unsigned short Ps[4][64 * ATTS];   // 36,864 B
    __shared__ __align__(16) float Mrg[2][64][81];              // 41,472 B

    const int t = threadIdx.x, w = t >> 6, lane = t & 63;
    const int quad = lane >> 4, c = lane & 15;
    const int bh = blockIdx.x & 63, bq = blockIdx.x >> 6;
    const int b = bh >> 4, hh = bh & 15;
    const size_t gbase = (size_t)bh * (2048 * 64);

    const int rs  = c & 3;
    const int rc0 = (quad ^ rs) * 8, rc1 = 32 + rc0;
    unsigned short* PsW = &Ps[w][0];

    // balanced segment table (see header comment)
    const int qtA = (w == 0) ? bq : (w == 1) ? (15 - bq) : (w == 2) ? (16 + bq) : (31 - bq);
    const int kA1 = (w == 0) ? (bq + 1) : (w == 1) ? (16 - bq) : 17;
    const int qtB = (w == 0) ? (31 - bq) : (16 + bq);   // waves 0/1 only
    const int kB1 = (w == 0) ? (32 - bq) : (17 + bq);

    v4f oacc[4][4], lacc[4];
    const short oneb = (short)0x3F80;  // bf16 1.0
    const v8s ones = {oneb, oneb, oneb, oneb, oneb, oneb, oneb, oneb};

    auto run_seg = [&](int qt, int k0, int k1) {
        const int qw = qt * 64;
        v8s qf[4][2];
#pragma unroll
        for (int qs = 0; qs < 4; ++qs) {
            const unsigned short* qp =
                Qbuf + gbase + (size_t)(qw + qs * 16 + c) * 64 + quad * 8;
            qf[qs][0] = *(const v8s*)qp;
            qf[qs][1] = *(const v8s*)(qp + 32);
        }
#pragma unroll
        for (int qs = 0; qs < 4; ++qs) {
            lacc[qs] = (v4f){0.f, 0.f, 0.f, 0.f};
#pragma unroll
            for (int dn = 0; dn < 4; ++dn) oacc[qs][dn] = (v4f){0.f, 0.f, 0.f, 0.f};
        }
        for (int kt = k0; kt < k1; ++kt) {
            const int kbase = kt * 64;
            const bool diag = (kt == qt);   // wave-uniform

            // V prefetch (vmcnt FIFO: the K wait also covers V arrival)
            v8s vf[4][2];
#pragma unroll
            for (int dn = 0; dn < 4; ++dn) {
                const unsigned short* vp =
                    VT + gbase + (size_t)(dn * 16 + c) * 2048 + kbase + quad * 8;
                vf[dn][0] = *(const v8s*)vp;
                vf[dn][1] = *(const v8s*)(vp + 32);
            }

            // S = Q K^T, P = exp2(S) streamed into Ps (A-layout via swizzle)
#pragma unroll
            for (int kn = 0; kn < 4; ++kn) {
                const unsigned short* kp =
                    Kbuf + gbase + (size_t)(kbase + kn * 16 + c) * 64 + quad * 8;
                v8s kf0 = *(const v8s*)kp;
                v8s kf1 = *(const v8s*)(kp + 32);
#pragma unroll
                for (int qs = 0; qs < 4; ++qs) {
                    v4f s = (v4f){0.f, 0.f, 0.f, 0.f};
                    s = __builtin_amdgcn_mfma_f32_16x16x32_bf16(qf[qs][0], kf0, s, 0, 0, 0);
                    s = __builtin_amdgcn_mfma_f32_16x16x32_bf16(qf[qs][1], kf1, s, 0, 0, 0);
                    if (diag) {
#pragma unroll
                        for (int r = 0; r < 4; ++r)
                            if (kn * 16 + c > qs * 16 + quad * 4 + r) s[r] = -1e30f;
                    }
#pragma unroll
                    for (int r = 0; r < 4; ++r) {
                        const float p = fast_exp2(s[r]);
                        PsW[(qs * 16 + quad * 4 + r) * ATTS +
                            (((2 * kn + (c >> 3)) ^ r) * 8) + (c & 7)] = f2bf_rh(p);
                    }
                }
            }
            // P fragments (A-layout), then O += P V and l += P @ ones
            v8s pa[4][2];
#pragma unroll
            for (int qs = 0; qs < 4; ++qs) {
                pa[qs][0] = *(const v8s*)&PsW[(qs * 16 + c) * ATTS + rc0];
                pa[qs][1] = *(const v8s*)&PsW[(qs * 16 + c) * ATTS + rc1];
            }
#pragma unroll
            for (int dn = 0; dn < 4; ++dn) {
#pragma unroll
                for (int qs = 0; qs < 4; ++qs) {
                    oacc[qs][dn] = __builtin_amdgcn_mfma_f32_16x16x32_bf16(pa[qs][0], vf[dn][0], oacc[qs][dn], 0, 0, 0);
                    oacc[qs][dn] = __builtin_amdgcn_mfma_f32_16x16x32_bf16(pa[qs][1], vf[dn][1], oacc[qs][dn], 0, 0, 0);
                }
            }
#pragma unroll
            for (int qs = 0; qs < 4; ++qs) {
                lacc[qs] = __builtin_amdgcn_mfma_f32_16x16x32_bf16(pa[qs][0], ones, lacc[qs], 0, 0, 0);
                lacc[qs] = __builtin_amdgcn_mfma_f32_16x16x32_bf16(pa[qs][1], ones, lacc[qs], 0, 0, 0);
            }
        }
    };

    auto store_final = [&](int qt) {
        const int qw = qt * 64;
#pragma unroll
        for (int qs = 0; qs < 4; ++qs) {
            float inv[4];
#pragma unroll
            for (int r = 0; r < 4; ++r) inv[r] = 1.f / lacc[qs][r];
            const size_t obase =
                ((size_t)(b * 2048 + qw + qs * 16 + quad * 4)) * DMODEL + hh * 64;
#pragma unroll
            for (int dn = 0; dn < 4; ++dn)
#pragma unroll
                for (int r = 0; r < 4; ++r)
                    sa[obase + (size_t)r * DMODEL + dn * 16 + c] = f2bf(oacc[qs][dn][r] * inv[r]);
        }
    };

    run_seg(qtA, 0, kA1);
    if (w < 2) {
        store_final(qtA);                 // complete q-tile
        run_seg(qtB, 17, kB1);            // tail of the long q-tile (may be empty)
        float* mg = &Mrg[w][lane][0];
#pragma unroll
        for (int qs = 0; qs < 4; ++qs) {
#pragma unroll
            for (int dn = 0; dn < 4; ++dn)
#pragma unroll
                for (int r = 0; r < 4; ++r) mg[qs * 16 + dn * 4 + r] = oacc[qs][dn][r];
#pragma unroll
            for (int r = 0; r < 4; ++r) mg[64 + qs * 4 + r] = lacc[qs][r];
        }
    }
    __syncthreads();                      // convergent: all 4 waves, exactly once
    if (w >= 2) {
        const float* mg = &Mrg[3 - w][lane][0];   // w=2 <- wave1's tail; w=3 <- wave0's
#pragma unroll
        for (int qs = 0; qs < 4; ++qs) {
#pragma unroll
            for (int dn = 0; dn < 4; ++dn)
#pragma unroll
                for (int r = 0; r < 4; ++r) oacc[qs][dn][r] += mg[qs * 16 + dn * 4 + r];
#pragma unroll
            for (int r = 0; r < 4; ++r) lacc[qs][r] += mg[64 + qs * 4 + r];
        }
        store_final(qtA);
    }
}

extern "C" void kernel_launch(void* const* d_in, const int* in_sizes, int n_in,
                              void* d_out, int out_size, void* d_ws, size_t ws_size,
                              hipStream_t stream) {
    const float* x     = (const float*)d_in[0];
    const float* Wkqv  = (const float*)d_in[1];
    const float* bkqv  = (const float*)d_in[2];
    const float* Wproj = (const float*)d_in[3];
    const float* bproj = (const float*)d_in[4];
    float* out = (float*)d_out;

    unsigned short* Kb = (unsigned short*)d_ws;        // [64][2048][64]
    unsigned short* Qb = Kb + (size_t)8388608;         // [64][2048][64]
    unsigned short* VT = Qb + (size_t)8388608;         // [64][64][2048]
    unsigned short* sa = VT + (size_t)8388608;         // [8192][1024]

    const bool fast = ws_size >= 75497472ull;          // 72 MiB
    if (fast) {
        unsigned short* xb  = sa;                      // xb dead before attn writes sa
        unsigned short* wkb = (unsigned short*)d_ws + (size_t)33554432;
        unsigned short* wpb = wkb + (size_t)3145728;
        cvt_bf16<<<12288, 256, 0, stream>>>(x, Wkqv, Wproj, xb, wkb, wpb);
        gemm_lds<1><<<dim3(12, 64), 512, 0, stream>>>(
            xb, wkb, bkqv, nullptr, Kb, Qb, VT, 8192, 3072, 1024);
        attn_mfma<<<512, 256, 0, stream>>>(Kb, Qb, VT, sa);
        gemm_lds<2><<<dim3(4, 64), 512, 0, stream>>>(
            sa, wpb, bproj, out, nullptr, nullptr, nullptr, 8192, 1024, 1024);
    } else {
        gemm_mfma<false, 1><<<dim3(24, 64), 256, 0, stream>>>(
            x, Wkqv, bkqv, nullptr, Kb, Qb, VT, 8192, 3072, 1024);
        attn_mfma<<<512, 256, 0, stream>>>(Kb, Qb, VT, sa);
        gemm_mfma<true, 2><<<dim3(8, 64), 256, 0, stream>>>(
            sa, Wproj, bproj, out, nullptr, nullptr, nullptr, 8192, 1024, 1024);
    }
}